// Round 1
// 169.078 us; speedup vs baseline: 1.5543x; 1.5543x over previous
//
#include <hip/hip_runtime.h>
#include <hip/hip_bf16.h>

#define B_ 4
#define C_ 128
#define N_ 4096
#define M_ 4096

typedef __bf16 bf16;
typedef __bf16 bf16x8 __attribute__((ext_vector_type(8)));
typedef float f32x4 __attribute__((ext_vector_type(4)));
typedef float f32x16 __attribute__((ext_vector_type(16)));

#define MFMA16(a, b, c) __builtin_amdgcn_mfma_f32_16x16x32_bf16(a, b, c, 0, 0, 0)
#define MFMA32(a, b, c) __builtin_amdgcn_mfma_f32_32x32x16_bf16(a, b, c, 0, 0, 0)

__device__ inline bf16x8 cvt8(const float* p8) {
    float4 a = *(const float4*)p8;
    float4 b = *(const float4*)(p8 + 4);
    bf16x8 r;
    r[0] = (bf16)a.x; r[1] = (bf16)a.y; r[2] = (bf16)a.z; r[3] = (bf16)a.w;
    r[4] = (bf16)b.x; r[5] = (bf16)b.y; r[6] = (bf16)b.z; r[7] = (bf16)b.w;
    return r;
}

// async 16B global -> LDS (dest = wave-uniform base + lane*16)
__device__ inline void gll16(const bf16* g, bf16* l) {
    __builtin_amdgcn_global_load_lds(
        (const __attribute__((address_space(1))) void*)g,
        (__attribute__((address_space(3))) void*)l, 16, 0, 0);
}

// ===========================================================================
// Kernel 1: fused projections (UNCHANGED this round — isolate attn delta).
// ===========================================================================
__global__ __launch_bounds__(768) void proj_kernel(
    const float* __restrict__ x1, const float* __restrict__ p1,
    const float* __restrict__ x2, const float* __restrict__ p2,
    const float* __restrict__ Wq, const float* __restrict__ Wk,
    const float* __restrict__ Wv, const float* __restrict__ Wpos,
    bf16* __restrict__ Qt, bf16* __restrict__ Kt, bf16* __restrict__ Vt) {
    __shared__ __align__(16) bf16 xp1[64 * 136];   // x1 + pos   17.4 KB
    __shared__ __align__(16) bf16 xp2[64 * 136];   // x2 + pos
    __shared__ __align__(16) bf16 xr2[64 * 136];   // x2 raw
    __shared__ float pp1[3 * 64], pp2[3 * 64], wls[384];

    const int t = threadIdx.x;
    const int b = blockIdx.y;
    const int n0 = blockIdx.x * 64;

    // ---- phase A: stage p1/p2/Wpos ----
    if (t < 48) {
        int k3 = t / 16, i4 = (t & 15) * 4;
        *(float4*)&pp1[k3 * 64 + i4] = *(const float4*)(p1 + ((size_t)b * 3 + k3) * N_ + n0 + i4);
    } else if (t < 96) {
        int tt = t - 48;
        int k3 = tt / 16, i4 = (tt & 15) * 4;
        *(float4*)&pp2[k3 * 64 + i4] = *(const float4*)(p2 + ((size_t)b * 3 + k3) * N_ + n0 + i4);
    } else if (t < 192) {
        int i4 = (t - 96) * 4;
        *(float4*)&wls[i4] = *(const float4*)(Wpos + i4);
    }
    __syncthreads();

    // ---- phase B: stage x tiles, fold pos, transpose to [n][c] bf16 ----
    for (int s = t; s < 2048; s += 768) {
        int c = s >> 4, n4 = (s & 15) * 4;
        float4 xv = *(const float4*)(x1 + ((size_t)b * C_ + c) * N_ + n0 + n4);
        float w0 = wls[c * 3 + 0], w1 = wls[c * 3 + 1], w2 = wls[c * 3 + 2];
        const float* xa = &xv.x;
        #pragma unroll
        for (int j = 0; j < 4; ++j) {
            float pos = w0 * pp1[n4 + j] + w1 * pp1[64 + n4 + j] + w2 * pp1[128 + n4 + j];
            xp1[(n4 + j) * 136 + c] = (bf16)(xa[j] + pos);
        }
    }
    for (int s = t; s < 2048; s += 768) {
        int c = s >> 4, n4 = (s & 15) * 4;
        float4 xv = *(const float4*)(x2 + ((size_t)b * C_ + c) * N_ + n0 + n4);
        float w0 = wls[c * 3 + 0], w1 = wls[c * 3 + 1], w2 = wls[c * 3 + 2];
        const float* xa = &xv.x;
        #pragma unroll
        for (int j = 0; j < 4; ++j) {
            float pos = w0 * pp2[n4 + j] + w1 * pp2[64 + n4 + j] + w2 * pp2[128 + n4 + j];
            xp2[(n4 + j) * 136 + c] = (bf16)(xa[j] + pos);
            xr2[(n4 + j) * 136 + c] = (bf16)xa[j];
        }
    }
    __syncthreads();

    // ---- phase C: MFMA per role ----
    const int w = t >> 6;
    const int lane = t & 63;
    const int col = lane & 15, quad = lane >> 4;
    const int role = w >> 2, band = w & 3;
    const int nl = band * 16 + col;
    const int n = n0 + nl;

    const bf16* src = (role == 0) ? xp1 : (role == 1) ? xp2 : xr2;
    const float* Wm = (role == 0) ? Wq : (role == 1) ? Wk : Wv;

    bf16x8 bx[4];
    #pragma unroll
    for (int cs = 0; cs < 4; ++cs)
        bx[cs] = *(const bf16x8*)&src[nl * 136 + cs * 32 + quad * 8];

    #pragma unroll
    for (int dt = 0; dt < 8; ++dt) {
        f32x4 acc = {0.f, 0.f, 0.f, 0.f};
        #pragma unroll
        for (int cs = 0; cs < 4; ++cs) {
            bf16x8 wf = cvt8(Wm + (dt * 16 + col) * 128 + cs * 32 + quad * 8);
            acc = MFMA16(wf, bx[cs], acc);
        }
        if (role < 2) {
            bf16* Ot = (role == 0) ? Qt : Kt;
            union { ushort4 u4; bf16 h[4]; } pk;
            #pragma unroll
            for (int r = 0; r < 4; ++r) pk.h[r] = (bf16)acc[r];
            *(ushort4*)(Ot + ((size_t)b * N_ + n) * C_ + dt * 16 + quad * 4) = pk.u4;
        } else {
            #pragma unroll
            for (int r = 0; r < 4; ++r)
                Vt[((size_t)b * C_ + dt * 16 + quad * 4 + r) * (size_t)M_ + n] = (bf16)acc[r];
        }
    }
}

// ===========================================================================
// Kernel 2 (REWRITTEN): flash attention, 32-query blocks, 4 waves, 32x32x16
// MFMA, 128-key chunks. Each wave owns a distinct 32-key group -> every K/V
// LDS byte is read exactly once (old: 4x band duplication). Staging goes
// through global_load_lds (width 16) with XOR-pre-swizzled SOURCE + linear
// LDS dest; reads apply the same XOR -> conflict-free ds_read_b128 and zero
// staging VGPRs. K-staging issues right after the post-QK barrier (hidden
// under exp/PV), V-staging right after the post-PV barrier (hidden under
// next QK); the __syncthreads auto vmcnt(0) drain is the visibility fence.
// Grid 512 = 2 blocks/CU (74 KB LDS) so barrier drains of one block are
// covered by the other. XCD swizzle: batch -> XCD pair, K+V (2 MB) L2-fit.
// ===========================================================================
__global__ __launch_bounds__(256, 2) void attn_kernel(
    const bf16* __restrict__ Qt, const bf16* __restrict__ Kt,
    const bf16* __restrict__ Vt, const float* __restrict__ x1,
    float* __restrict__ out) {
    __shared__ __align__(16) char smem[75776];
    bf16* kb = (bf16*)smem;              // [128 key][128 c], seg ^= key&7, 32 KB
    bf16* vb = (bf16*)(smem + 32768);    // [128 c][128 key], seg ^= c&7,   32 KB
    bf16* pb = (bf16*)(smem + 65536);    // 4 waves x [32 q][40 k]          10 KB

    const int t = threadIdx.x;
    const int w = t >> 6;           // wave = key-group (32 keys of the chunk)
    const int lane = t & 63;
    const int col = lane & 31;
    const int hi = lane >> 5;

    // XCD-aware decode: batch -> XCD pair so each XCD's L2 holds one batch's K+V
    const int g0 = blockIdx.x;
    const int xcd = g0 & 7;
    const int b = xcd >> 1;
    const int qt = (xcd & 1) + ((g0 >> 3) << 1);  // 128 query tiles of 32
    const int n0 = qt * 32;

    const float KS = 0.12752107168406815f;  // log2(e)/sqrt(128)

    const bf16* Kbase = Kt + (size_t)b * M_ * C_;
    const bf16* Vbase = Vt + (size_t)b * C_ * M_;

    // Q fragments (A-operand): row = col (query), k = cs*16 + hi*8 + j
    bf16x8 qf[8];
    {
        const bf16* Qb = Qt + ((size_t)b * N_ + n0 + col) * C_ + hi * 8;
        #pragma unroll
        for (int cs = 0; cs < 8; ++cs)
            qf[cs] = *(const bf16x8*)(Qb + cs * 16);
    }

    f32x16 oacc[4];
    #pragma unroll
    for (int i = 0; i < 4; ++i)
        #pragma unroll
        for (int j = 0; j < 16; ++j) oacc[i][j] = 0.f;
    float lacc[16];
    #pragma unroll
    for (int r = 0; r < 16; ++r) lacc[r] = 0.f;

    // per-lane K read base: this wave's key = w*32 + col
    const int key_l = (w << 5) + col;
    const char* kbp = (const char*)kb + key_l * 256;
    const int kxor = (key_l & 7) << 4;
    bf16* pbw = pb + w * 1280;      // [32 q][40 k], stride 40 -> 16B-aligned rows

    // staging: 2048 16B-segs per tile, wave w covers segs [w*512, w*512+512)
    auto stageK = [&](int m0) {
        #pragma unroll
        for (int i = 0; i < 8; ++i) {
            int g = ((w << 3) + i) * 64 + lane;
            int key = g >> 4;
            int sp = (g & 15) ^ (key & 7);   // inverse-swizzled SOURCE
            gll16(Kbase + (size_t)(m0 + key) * C_ + sp * 8, kb + ((w << 3) + i) * 512);
        }
    };
    auto stageV = [&](int m0) {
        #pragma unroll
        for (int i = 0; i < 8; ++i) {
            int g = ((w << 3) + i) * 64 + lane;
            int c = g >> 4;
            int sp = (g & 15) ^ (c & 7);
            gll16(Vbase + (size_t)c * M_ + m0 + sp * 8, vb + ((w << 3) + i) * 512);
        }
    };

    stageK(0);
    stageV(0);
    __syncthreads();   // auto vmcnt(0) drains the gll writes

    for (int ch = 0; ch < 32; ++ch) {
        // ---- S = Q K^T : 32q x 32k over this wave's key group ----
        f32x16 sacc;
        #pragma unroll
        for (int j = 0; j < 16; ++j) sacc[j] = 0.f;
        __builtin_amdgcn_s_setprio(1);
        #pragma unroll
        for (int cs = 0; cs < 8; ++cs) {
            bf16x8 kf = *(const bf16x8*)(kbp + ((((cs << 1) + hi) << 4) ^ kxor));
            sacc = MFMA32(qf[cs], kf, sacc);
        }
        __builtin_amdgcn_s_setprio(0);

        __syncthreads();                        // A: all kb reads done
        if (ch < 31) stageK((ch + 1) << 7);     // K(ch+1) hides under exp/PV

        // ---- P = exp2(S*KS): lane holds S[q(r,hi)][key=col] ----
        #pragma unroll
        for (int r = 0; r < 16; ++r) {
            float e = fminf(sacc[r] * KS, 60.f);
            float p = __builtin_amdgcn_exp2f(e);
            lacc[r] += p;
            int q = (r & 3) + ((r >> 2) << 3) + (hi << 2);
            pbw[q * 40 + col] = (bf16)p;
        }
        asm volatile("s_waitcnt lgkmcnt(0)" ::: "memory");

        // A-frags for PV: row = q = col, k = ks*16 + hi*8 + j
        bf16x8 af0 = *(const bf16x8*)&pbw[col * 40 + hi * 8];
        bf16x8 af1 = *(const bf16x8*)&pbw[col * 40 + 16 + hi * 8];

        // ---- O += P V^T ----
        __builtin_amdgcn_s_setprio(1);
        #pragma unroll
        for (int ct = 0; ct < 4; ++ct) {
            int c = (ct << 5) + col;
            const char* vbp = (const char*)vb + c * 256;
            int vxor = (c & 7) << 4;
            bf16x8 vf0 = *(const bf16x8*)(vbp + ((((w << 2) + hi) << 4) ^ vxor));
            bf16x8 vf1 = *(const bf16x8*)(vbp + ((((w << 2) + 2 + hi) << 4) ^ vxor));
            oacc[ct] = MFMA32(af0, vf0, oacc[ct]);
            oacc[ct] = MFMA32(af1, vf1, oacc[ct]);
        }
        __builtin_amdgcn_s_setprio(0);

        __syncthreads();                        // B: vb reads done, K-gll drained
        if (ch < 31) stageV((ch + 1) << 7);     // V(ch+1) hides under next QK
    }

    __syncthreads();   // all LDS reads retired; re-use smem for the merge

    // ---- cross-wave merge of key-group partials ----
    float* obuf = (float*)smem;                 // [4 waves][32 q][132 c]  66 KB
    float* lps  = (float*)(smem + 67584);       // [4 waves][32 q]

    #pragma unroll
    for (int r = 0; r < 16; ++r)
        #pragma unroll
        for (int off = 1; off < 32; off <<= 1)
            lacc[r] += __shfl_xor(lacc[r], off, 64);   // sum over 32 key-lanes

    if (col == 0) {
        #pragma unroll
        for (int r = 0; r < 16; ++r) {
            int q = (r & 3) + ((r >> 2) << 3) + (hi << 2);
            lps[(w << 5) + q] = lacc[r];
        }
    }
    #pragma unroll
    for (int ct = 0; ct < 4; ++ct)
        #pragma unroll
        for (int r = 0; r < 16; ++r) {
            int q = (r & 3) + ((r >> 2) << 3) + (hi << 2);
            obuf[w * 4224 + q * 132 + (ct << 5) + col] = oacc[ct][r];
        }
    __syncthreads();

    const int c2 = lane << 1;                   // 2 channels per lane
    #pragma unroll
    for (int j = 0; j < 8; ++j) {
        int q = (w << 3) + j;                   // wave w finalizes queries w*8..w*8+7
        float s0 = 0.f, s1 = 0.f;
        #pragma unroll
        for (int p = 0; p < 4; ++p) {
            s0 += obuf[p * 4224 + q * 132 + c2];
            s1 += obuf[p * 4224 + q * 132 + c2 + 1];
        }
        float lsum = lps[q] + lps[32 + q] + lps[64 + q] + lps[96 + q];
        float linv = 1.0f / lsum;
        int n = n0 + q;
        float o0 = s0 * linv + x1[((size_t)b * C_ + c2) * N_ + n];
        float o1 = s1 * linv + x1[((size_t)b * C_ + c2 + 1) * N_ + n];
        *(float2*)&out[((size_t)b * N_ + n) * C_ + c2] = make_float2(o0, o1);
    }
}

// ---------------------------------------------------------------------------
extern "C" void kernel_launch(void* const* d_in, const int* in_sizes, int n_in,
                              void* d_out, int out_size, void* d_ws, size_t ws_size,
                              hipStream_t stream) {
    const float* x1   = (const float*)d_in[0];
    const float* p1   = (const float*)d_in[1];
    const float* x2   = (const float*)d_in[2];
    const float* p2   = (const float*)d_in[3];
    const float* Wq   = (const float*)d_in[4];
    const float* Wk   = (const float*)d_in[5];
    const float* Wv   = (const float*)d_in[6];
    const float* Wpos = (const float*)d_in[7];
    float* out = (float*)d_out;

    bf16* Qt = (bf16*)d_ws;                 // [B][N][C]
    bf16* Kt = Qt + (size_t)B_ * N_ * C_;   // [B][M][C]
    bf16* Vt = Kt + (size_t)B_ * M_ * C_;   // [B][C][M]

    proj_kernel<<<dim3(64, B_), dim3(768), 0, stream>>>(
        x1, p1, x2, p2, Wq, Wk, Wv, Wpos, Qt, Kt, Vt);
    attn_kernel<<<dim3(512), dim3(256), 0, stream>>>(Qt, Kt, Vt, x1, out);
}

// Round 3
// 152.781 us; speedup vs baseline: 1.7201x; 1.1067x over previous
//
#include <hip/hip_runtime.h>
#include <hip/hip_bf16.h>

#define B_ 4
#define C_ 128
#define N_ 4096
#define M_ 4096

typedef __bf16 bf16;
typedef __bf16 bf16x8 __attribute__((ext_vector_type(8)));
typedef float f32x4 __attribute__((ext_vector_type(4)));
typedef float f32x16 __attribute__((ext_vector_type(16)));

#define MFMA16(a, b, c) __builtin_amdgcn_mfma_f32_16x16x32_bf16(a, b, c, 0, 0, 0)
#define MFMA32(a, b, c) __builtin_amdgcn_mfma_f32_32x32x16_bf16(a, b, c, 0, 0, 0)

// async 16B global -> LDS (dest = wave-uniform base + lane*16)
__device__ inline void gll16(const bf16* g, bf16* l) {
    __builtin_amdgcn_global_load_lds(
        (const __attribute__((address_space(1))) void*)g,
        (__attribute__((address_space(3))) void*)l, 16, 0, 0);
}

// v_cvt_pk_bf16_f32: pack two f32 -> u32 of 2 bf16 (lo = a, hi = b)
__device__ inline unsigned cvtpk(float a, float b) {
    unsigned r;
    asm("v_cvt_pk_bf16_f32 %0, %1, %2" : "=v"(r) : "v"(a), "v"(b));
    return r;
}

// ===========================================================================
// Kernel 0: one-shot W f32->bf16 conversion (same element layout => same
// rounding as the old per-fragment cvt8). Output parked in the head of
// d_out (8 MB), which attn_kernel fully overwrites afterwards — avoids any
// assumption about ws_size headroom. 48 blocks x 256 thr, ~2 us.
// ===========================================================================
__global__ __launch_bounds__(256) void wcvt_kernel(
    const float* __restrict__ Wq, const float* __restrict__ Wk,
    const float* __restrict__ Wv, bf16* __restrict__ Wb) {
    int i = (blockIdx.x * 256 + threadIdx.x) * 4;        // 49152 elements total
    const float* src = (i < 16384) ? Wq : (i < 32768) ? Wk : Wv;
    int off = i & 16383;
    float4 v = *(const float4*)(src + off);
    union { ushort4 u4; bf16 h[4]; } pk;
    pk.h[0] = (bf16)v.x; pk.h[1] = (bf16)v.y;
    pk.h[2] = (bf16)v.z; pk.h[3] = (bf16)v.w;
    *(ushort4*)(Wb + i) = pk.u4;
}

// ===========================================================================
// Kernel 1: fused projections. Change this round: phase C reads PRE-CONVERTED
// bf16 W fragments (single 16B load, L1-hot) instead of 2x float4 + 8 cvt
// per fragment on the acc critical path. Indexing identical to the f32 path.
// ===========================================================================
__global__ __launch_bounds__(768) void proj_kernel(
    const float* __restrict__ x1, const float* __restrict__ p1,
    const float* __restrict__ x2, const float* __restrict__ p2,
    const bf16* __restrict__ Wb, const float* __restrict__ Wpos,
    bf16* __restrict__ Qt, bf16* __restrict__ Kt, bf16* __restrict__ Vt) {
    __shared__ __align__(16) bf16 xp1[64 * 136];   // x1 + pos   17.4 KB
    __shared__ __align__(16) bf16 xp2[64 * 136];   // x2 + pos
    __shared__ __align__(16) bf16 xr2[64 * 136];   // x2 raw
    __shared__ float pp1[3 * 64], pp2[3 * 64], wls[384];

    const int t = threadIdx.x;
    const int b = blockIdx.y;
    const int n0 = blockIdx.x * 64;

    // ---- phase A: stage p1/p2/Wpos ----
    if (t < 48) {
        int k3 = t / 16, i4 = (t & 15) * 4;
        *(float4*)&pp1[k3 * 64 + i4] = *(const float4*)(p1 + ((size_t)b * 3 + k3) * N_ + n0 + i4);
    } else if (t < 96) {
        int tt = t - 48;
        int k3 = tt / 16, i4 = (tt & 15) * 4;
        *(float4*)&pp2[k3 * 64 + i4] = *(const float4*)(p2 + ((size_t)b * 3 + k3) * N_ + n0 + i4);
    } else if (t < 192) {
        int i4 = (t - 96) * 4;
        *(float4*)&wls[i4] = *(const float4*)(Wpos + i4);
    }
    __syncthreads();

    // ---- phase B: stage x tiles, fold pos, transpose to [n][c] bf16 ----
    for (int s = t; s < 2048; s += 768) {
        int c = s >> 4, n4 = (s & 15) * 4;
        float4 xv = *(const float4*)(x1 + ((size_t)b * C_ + c) * N_ + n0 + n4);
        float w0 = wls[c * 3 + 0], w1 = wls[c * 3 + 1], w2 = wls[c * 3 + 2];
        const float* xa = &xv.x;
        #pragma unroll
        for (int j = 0; j < 4; ++j) {
            float pos = w0 * pp1[n4 + j] + w1 * pp1[64 + n4 + j] + w2 * pp1[128 + n4 + j];
            xp1[(n4 + j) * 136 + c] = (bf16)(xa[j] + pos);
        }
    }
    for (int s = t; s < 2048; s += 768) {
        int c = s >> 4, n4 = (s & 15) * 4;
        float4 xv = *(const float4*)(x2 + ((size_t)b * C_ + c) * N_ + n0 + n4);
        float w0 = wls[c * 3 + 0], w1 = wls[c * 3 + 1], w2 = wls[c * 3 + 2];
        const float* xa = &xv.x;
        #pragma unroll
        for (int j = 0; j < 4; ++j) {
            float pos = w0 * pp2[n4 + j] + w1 * pp2[64 + n4 + j] + w2 * pp2[128 + n4 + j];
            xp2[(n4 + j) * 136 + c] = (bf16)(xa[j] + pos);
            xr2[(n4 + j) * 136 + c] = (bf16)xa[j];
        }
    }
    __syncthreads();

    // ---- phase C: MFMA per role ----
    const int w = t >> 6;
    const int lane = t & 63;
    const int col = lane & 15, quad = lane >> 4;
    const int role = w >> 2, band = w & 3;
    const int nl = band * 16 + col;
    const int n = n0 + nl;

    const bf16* src = (role == 0) ? xp1 : (role == 1) ? xp2 : xr2;
    const bf16* Wm = Wb + role * 16384;   // bf16 W, same [row][col] layout

    bf16x8 bx[4];
    #pragma unroll
    for (int cs = 0; cs < 4; ++cs)
        bx[cs] = *(const bf16x8*)&src[nl * 136 + cs * 32 + quad * 8];

    #pragma unroll
    for (int dt = 0; dt < 8; ++dt) {
        f32x4 acc = {0.f, 0.f, 0.f, 0.f};
        #pragma unroll
        for (int cs = 0; cs < 4; ++cs) {
            bf16x8 wf = *(const bf16x8*)(Wm + (dt * 16 + col) * 128 + cs * 32 + quad * 8);
            acc = MFMA16(wf, bx[cs], acc);
        }
        if (role < 2) {
            bf16* Ot = (role == 0) ? Qt : Kt;
            union { ushort4 u4; bf16 h[4]; } pk;
            #pragma unroll
            for (int r = 0; r < 4; ++r) pk.h[r] = (bf16)acc[r];
            *(ushort4*)(Ot + ((size_t)b * N_ + n) * C_ + dt * 16 + quad * 4) = pk.u4;
        } else {
            #pragma unroll
            for (int r = 0; r < 4; ++r)
                Vt[((size_t)b * C_ + dt * 16 + quad * 4 + r) * (size_t)M_ + n] = (bf16)acc[r];
        }
    }
}

// ===========================================================================
// Kernel 2 (v2, hardened): counted-vmcnt pipeline + in-register softmax
// transpose. vs v2: explicit lgkmcnt(0)+sched_barrier fences before each
// restage of the single-buffered kb/vb tiles (ordering by construction, not
// by timing), sched_barrier(0) after every inline-asm waitcnt (rule #18).
// ===========================================================================
__global__ __launch_bounds__(256, 2) void attn_kernel(
    const bf16* __restrict__ Qt, const bf16* __restrict__ Kt,
    const bf16* __restrict__ Vt, const float* __restrict__ x1,
    float* __restrict__ out) {
    __shared__ __align__(16) char smem[66048];
    bf16* kb = (bf16*)smem;              // [128 key][16 slots, slot^=key&15] 32KB
    bf16* vb = (bf16*)(smem + 32768);    // [128 c ][16 slots, slot^=c&15]   32KB

    const int t = threadIdx.x;
    const int w = t >> 6;           // wave = 32-key group of the 128-key chunk
    const int lane = t & 63;
    const int col = lane & 31;
    const int hi = lane >> 5;

    // XCD-aware decode: batch -> XCD pair so each XCD's L2 holds one batch's K+V
    const int g0 = blockIdx.x;
    const int xcd = g0 & 7;
    const int b = xcd >> 1;
    const int qt = (xcd & 1) + ((g0 >> 3) << 1);
    const int n0 = qt * 32;

    const float KS = 0.12752107168406815f;  // log2(e)/sqrt(128)

    const bf16* Kbase = Kt + (size_t)b * M_ * C_;
    const bf16* Vbase = Vt + (size_t)b * C_ * M_;

    // Q fragments (B-operand of swapped QK): lane col = query, k = hi*8+j
    bf16x8 qf[8];
    {
        const bf16* Qb = Qt + ((size_t)b * N_ + n0 + col) * C_ + hi * 8;
        #pragma unroll
        for (int cs = 0; cs < 8; ++cs)
            qf[cs] = *(const bf16x8*)(Qb + cs * 16);
    }

    f32x16 oacc[4];
    #pragma unroll
    for (int i = 0; i < 4; ++i)
        #pragma unroll
        for (int j = 0; j < 16; ++j) oacc[i][j] = 0.f;
    float lacc = 0.f;

    const int key_l = (w << 5) + col;
    const char* kbp = (const char*)kb + key_l * 256;
    const int kxor = (key_l & 15) << 4;

    auto stageK = [&](int m0) {
        #pragma unroll
        for (int i = 0; i < 8; ++i) {
            int g = ((w << 3) + i) * 64 + lane;
            int key = g >> 4;
            int sp = (g & 15) ^ (key & 15);   // inverse-swizzled SOURCE
            gll16(Kbase + (size_t)(m0 + key) * C_ + sp * 8, kb + ((w << 3) + i) * 512);
        }
    };
    auto stageV = [&](int m0) {
        #pragma unroll
        for (int i = 0; i < 8; ++i) {
            int g = ((w << 3) + i) * 64 + lane;
            int c = g >> 4;
            int sp = (g & 15) ^ (c & 15);
            gll16(Vbase + (size_t)c * M_ + m0 + sp * 8, vb + ((w << 3) + i) * 512);
        }
    };

    stageK(0);          // oldest 8 in flight
    stageV(0);          // next 8

    for (int ch = 0; ch < 32; ++ch) {
        // own K(ch) landed (oldest 8 of 16); V(ch) may still fly
        asm volatile("s_waitcnt vmcnt(8)" ::: "memory");
        __builtin_amdgcn_sched_barrier(0);

        // ---- S^T = K Q : D lane = query, rows = keys (swapped operands) ----
        f32x16 s0a, s1a;
        #pragma unroll
        for (int j = 0; j < 16; ++j) { s0a[j] = 0.f; s1a[j] = 0.f; }
        __builtin_amdgcn_s_setprio(1);
        #pragma unroll
        for (int cs = 0; cs < 4; ++cs) {
            bf16x8 kf = *(const bf16x8*)(kbp + ((((cs << 1) + hi) << 4) ^ kxor));
            s0a = MFMA32(kf, qf[cs], s0a);
        }
        #pragma unroll
        for (int cs = 4; cs < 8; ++cs) {
            bf16x8 kf = *(const bf16x8*)(kbp + ((((cs << 1) + hi) << 4) ^ kxor));
            s1a = MFMA32(kf, qf[cs], s1a);
        }
        __builtin_amdgcn_s_setprio(0);

        // kb is wave-private, single-buffered: guarantee this wave's kb reads
        // RETIRED before restage can land (ordering by construction)
        if (ch < 31) {
            asm volatile("s_waitcnt lgkmcnt(0)" ::: "memory");
            __builtin_amdgcn_sched_barrier(0);
            stageK((ch + 1) << 7);
        }

        // ---- P = exp2(S*KS); lane(q=col,hi) holds keys (r&3)+8(r>>2)+4hi ----
        float p[16];
        #pragma unroll
        for (int r = 0; r < 16; ++r) {
            float e = fminf((s0a[r] + s1a[r]) * KS, 60.f);
            p[r] = __builtin_amdgcn_exp2f(e);
        }
        // row-sum (tree) — full 32-key sum finished with one shfl in epilogue
        {
            float s01 = (p[0] + p[1]) + (p[2] + p[3]);
            float s23 = (p[4] + p[5]) + (p[6] + p[7]);
            float s45 = (p[8] + p[9]) + (p[10] + p[11]);
            float s67 = (p[12] + p[13]) + (p[14] + p[15]);
            lacc += (s01 + s23) + (s45 + s67);
        }
        // pack to bf16 pairs: W0..W7; quads Q0=W0W1 Q1=W2W3 Q2=W4W5 Q3=W6W7
        unsigned W0 = cvtpk(p[0], p[1]),  W1 = cvtpk(p[2], p[3]);
        unsigned W2 = cvtpk(p[4], p[5]),  W3 = cvtpk(p[6], p[7]);
        unsigned W4 = cvtpk(p[8], p[9]),  W5 = cvtpk(p[10], p[11]);
        unsigned W6 = cvtpk(p[12], p[13]), W7 = cvtpk(p[14], p[15]);
        // cross-hi exchange: hi=0 sends W2,W3 / W6,W7; hi=1 sends W0,W1 / W4,W5
        unsigned X0 = hi ? W0 : W2, X1 = hi ? W1 : W3;
        unsigned Y0 = hi ? W4 : W6, Y1 = hi ? W5 : W7;
        X0 = __shfl_xor(X0, 32, 64);  X1 = __shfl_xor(X1, 32, 64);
        Y0 = __shfl_xor(Y0, 32, 64);  Y1 = __shfl_xor(Y1, 32, 64);
        uint4 u0, u1;
        u0.x = hi ? X0 : W0;  u0.y = hi ? X1 : W1;
        u0.z = hi ? W2 : X0;  u0.w = hi ? W3 : X1;
        u1.x = hi ? Y0 : W4;  u1.y = hi ? Y1 : W5;
        u1.z = hi ? W6 : Y0;  u1.w = hi ? W7 : Y1;
        bf16x8 af0 = __builtin_bit_cast(bf16x8, u0);   // keys hi*8   .. +7
        bf16x8 af1 = __builtin_bit_cast(bf16x8, u1);   // keys 16+hi*8.. +7

        // own V(ch) landed; after barrier ALL waves' V(ch) landed
        if (ch < 31) asm volatile("s_waitcnt vmcnt(8)" ::: "memory");
        else         asm volatile("s_waitcnt vmcnt(0)" ::: "memory");
        __builtin_amdgcn_sched_barrier(0);
        __builtin_amdgcn_s_barrier();

        // ---- O += P V^T ----
        __builtin_amdgcn_s_setprio(1);
        #pragma unroll
        for (int ct = 0; ct < 4; ++ct) {
            int c = (ct << 5) + col;
            const char* vbp = (const char*)vb + c * 256;
            int vxor = (c & 15) << 4;
            bf16x8 vf0 = *(const bf16x8*)(vbp + ((((w << 2) + hi) << 4) ^ vxor));
            bf16x8 vf1 = *(const bf16x8*)(vbp + ((((w << 2) + 2 + hi) << 4) ^ vxor));
            oacc[ct] = MFMA32(af0, vf0, oacc[ct]);
            oacc[ct] = MFMA32(af1, vf1, oacc[ct]);
        }
        __builtin_amdgcn_s_setprio(0);

        // vb reads retired before ANY wave restages (fence + barrier)
        asm volatile("s_waitcnt lgkmcnt(0)" ::: "memory");
        __builtin_amdgcn_sched_barrier(0);
        __builtin_amdgcn_s_barrier();
        if (ch < 31) stageV((ch + 1) << 7);
    }

    __builtin_amdgcn_s_barrier();   // all LDS reads retired; reuse smem

    // ---- cross-wave merge of key-group partials ----
    float* obuf = (float*)smem;                 // [4 waves][32 q][128 c]  64 KB
    float* lps  = (float*)(smem + 65536);       // [4 waves][32 q]

    lacc += __shfl_xor(lacc, 32, 64);           // + other hi-half's 16 keys
    if (hi == 0) lps[(w << 5) + col] = lacc;

    #pragma unroll
    for (int ct = 0; ct < 4; ++ct)
        #pragma unroll
        for (int r = 0; r < 16; ++r) {
            int q = (r & 3) + ((r >> 2) << 3) + (hi << 2);
            obuf[w * 4096 + q * 128 + (ct << 5) + col] = oacc[ct][r];
        }
    __syncthreads();

    const int c2 = lane << 1;                   // 2 channels per lane
    #pragma unroll
    for (int j = 0; j < 8; ++j) {
        int q = (w << 3) + j;                   // wave w finalizes queries w*8..+7
        float s0 = 0.f, s1 = 0.f;
        #pragma unroll
        for (int pp = 0; pp < 4; ++pp) {
            float2 v = *(const float2*)&obuf[pp * 4096 + q * 128 + c2];
            s0 += v.x; s1 += v.y;
        }
        float lsum = lps[q] + lps[32 + q] + lps[64 + q] + lps[96 + q];
        float linv = 1.0f / lsum;
        int n = n0 + q;
        float o0 = s0 * linv + x1[((size_t)b * C_ + c2) * N_ + n];
        float o1 = s1 * linv + x1[((size_t)b * C_ + c2 + 1) * N_ + n];
        *(float2*)&out[((size_t)b * N_ + n) * C_ + c2] = make_float2(o0, o1);
    }
}

// ---------------------------------------------------------------------------
extern "C" void kernel_launch(void* const* d_in, const int* in_sizes, int n_in,
                              void* d_out, int out_size, void* d_ws, size_t ws_size,
                              hipStream_t stream) {
    const float* x1   = (const float*)d_in[0];
    const float* p1   = (const float*)d_in[1];
    const float* x2   = (const float*)d_in[2];
    const float* p2   = (const float*)d_in[3];
    const float* Wq   = (const float*)d_in[4];
    const float* Wk   = (const float*)d_in[5];
    const float* Wv   = (const float*)d_in[6];
    const float* Wpos = (const float*)d_in[7];
    float* out = (float*)d_out;

    bf16* Qt = (bf16*)d_ws;                 // [B][N][C]
    bf16* Kt = Qt + (size_t)B_ * N_ * C_;   // [B][M][C]
    bf16* Vt = Kt + (size_t)B_ * M_ * C_;   // [B][C][M]

    // bf16 W parked in the head of out (96 KB of 8 MB); proj reads it, then
    // attn fully overwrites out. No ws_size headroom assumptions.
    bf16* Wb = (bf16*)d_out;

    wcvt_kernel<<<dim3(48), dim3(256), 0, stream>>>(Wq, Wk, Wv, Wb);
    proj_kernel<<<dim3(64, B_), dim3(768), 0, stream>>>(
        x1, p1, x2, p2, Wb, Wpos, Qt, Kt, Vt);
    attn_kernel<<<dim3(512), dim3(256), 0, stream>>>(Qt, Kt, Vt, x1, out);
}

// Round 4
// 146.335 us; speedup vs baseline: 1.7959x; 1.0441x over previous
//
#include <hip/hip_runtime.h>
#include <hip/hip_bf16.h>

#define B_ 4
#define C_ 128
#define N_ 4096
#define M_ 4096

typedef __bf16 bf16;
typedef __bf16 bf16x8 __attribute__((ext_vector_type(8)));
typedef float f32x4 __attribute__((ext_vector_type(4)));
typedef float f32x16 __attribute__((ext_vector_type(16)));

#define MFMA16(a, b, c) __builtin_amdgcn_mfma_f32_16x16x32_bf16(a, b, c, 0, 0, 0)
#define MFMA32(a, b, c) __builtin_amdgcn_mfma_f32_32x32x16_bf16(a, b, c, 0, 0, 0)

// async 16B global -> LDS (dest = wave-uniform base + lane*16)
__device__ inline void gll16(const bf16* g, bf16* l) {
    __builtin_amdgcn_global_load_lds(
        (const __attribute__((address_space(1))) void*)g,
        (__attribute__((address_space(3))) void*)l, 16, 0, 0);
}

// v_cvt_pk_bf16_f32: pack two f32 -> u32 of 2 bf16 (lo = a, hi = b)
__device__ inline unsigned cvtpk(float a, float b) {
    unsigned r;
    asm("v_cvt_pk_bf16_f32 %0, %1, %2" : "=v"(r) : "v"(a), "v"(b));
    return r;
}

// ===========================================================================
// Kernel 0: one-shot W f32->bf16 conversion (parked in head of d_out, which
// attn fully overwrites later).
// ===========================================================================
__global__ __launch_bounds__(256) void wcvt_kernel(
    const float* __restrict__ Wq, const float* __restrict__ Wk,
    const float* __restrict__ Wv, bf16* __restrict__ Wb) {
    int i = (blockIdx.x * 256 + threadIdx.x) * 4;        // 49152 elements total
    const float* src = (i < 16384) ? Wq : (i < 32768) ? Wk : Wv;
    int off = i & 16383;
    float4 v = *(const float4*)(src + off);
    union { ushort4 u4; bf16 h[4]; } pk;
    pk.h[0] = (bf16)v.x; pk.h[1] = (bf16)v.y;
    pk.h[2] = (bf16)v.z; pk.h[3] = (bf16)v.w;
    *(ushort4*)(Wb + i) = pk.u4;
}

// ===========================================================================
// Kernel 1: fused projections. Change this round: V output leaves through an
// LDS transpose tile (vt aliases xp1/xp2 after fragments are in regs) as
// coalesced 16B dwordx4 stores, replacing 32 scalar 2B global stores/lane.
// ===========================================================================
__global__ __launch_bounds__(768) void proj_kernel(
    const float* __restrict__ x1, const float* __restrict__ p1,
    const float* __restrict__ x2, const float* __restrict__ p2,
    const bf16* __restrict__ Wb, const float* __restrict__ Wpos,
    bf16* __restrict__ Qt, bf16* __restrict__ Kt, bf16* __restrict__ Vt) {
    __shared__ __align__(16) bf16 xbuf[3 * 64 * 136];   // 52.2 KB
    bf16* xp1 = xbuf;                  // x1 + pos   [n][c] stride 136
    bf16* xp2 = xbuf + 8704;           // x2 + pos
    bf16* xr2 = xbuf + 17408;          // x2 raw
    __shared__ float pp1[3 * 64], pp2[3 * 64], wls[384];

    const int t = threadIdx.x;
    const int b = blockIdx.y;
    const int n0 = blockIdx.x * 64;

    // ---- phase A: stage p1/p2/Wpos ----
    if (t < 48) {
        int k3 = t / 16, i4 = (t & 15) * 4;
        *(float4*)&pp1[k3 * 64 + i4] = *(const float4*)(p1 + ((size_t)b * 3 + k3) * N_ + n0 + i4);
    } else if (t < 96) {
        int tt = t - 48;
        int k3 = tt / 16, i4 = (tt & 15) * 4;
        *(float4*)&pp2[k3 * 64 + i4] = *(const float4*)(p2 + ((size_t)b * 3 + k3) * N_ + n0 + i4);
    } else if (t < 192) {
        int i4 = (t - 96) * 4;
        *(float4*)&wls[i4] = *(const float4*)(Wpos + i4);
    }
    __syncthreads();

    // ---- phase B: stage x tiles, fold pos, transpose to [n][c] bf16 ----
    for (int s = t; s < 2048; s += 768) {
        int c = s >> 4, n4 = (s & 15) * 4;
        float4 xv = *(const float4*)(x1 + ((size_t)b * C_ + c) * N_ + n0 + n4);
        float w0 = wls[c * 3 + 0], w1 = wls[c * 3 + 1], w2 = wls[c * 3 + 2];
        const float* xa = &xv.x;
        #pragma unroll
        for (int j = 0; j < 4; ++j) {
            float pos = w0 * pp1[n4 + j] + w1 * pp1[64 + n4 + j] + w2 * pp1[128 + n4 + j];
            xp1[(n4 + j) * 136 + c] = (bf16)(xa[j] + pos);
        }
    }
    for (int s = t; s < 2048; s += 768) {
        int c = s >> 4, n4 = (s & 15) * 4;
        float4 xv = *(const float4*)(x2 + ((size_t)b * C_ + c) * N_ + n0 + n4);
        float w0 = wls[c * 3 + 0], w1 = wls[c * 3 + 1], w2 = wls[c * 3 + 2];
        const float* xa = &xv.x;
        #pragma unroll
        for (int j = 0; j < 4; ++j) {
            float pos = w0 * pp2[n4 + j] + w1 * pp2[64 + n4 + j] + w2 * pp2[128 + n4 + j];
            xp2[(n4 + j) * 136 + c] = (bf16)(xa[j] + pos);
            xr2[(n4 + j) * 136 + c] = (bf16)xa[j];
        }
    }
    __syncthreads();

    // ---- phase C: MFMA per role ----
    const int w = t >> 6;
    const int lane = t & 63;
    const int col = lane & 15, quad = lane >> 4;
    const int role = w >> 2, band = w & 3;
    const int nl = band * 16 + col;
    const int n = n0 + nl;

    const bf16* src = (role == 0) ? xp1 : (role == 1) ? xp2 : xr2;
    const bf16* Wm = Wb + role * 16384;   // bf16 W, same [row][col] layout

    bf16x8 bx[4];
    #pragma unroll
    for (int cs = 0; cs < 4; ++cs)
        bx[cs] = *(const bf16x8*)&src[nl * 136 + cs * 32 + quad * 8];

    __syncthreads();          // B1: all fragments in regs; xbuf reusable as vt
    bf16* vt = xbuf;          // [128 c][72 n-slots] (9216 elems <= region)

    #pragma unroll
    for (int dt = 0; dt < 8; ++dt) {
        f32x4 acc = {0.f, 0.f, 0.f, 0.f};
        #pragma unroll
        for (int cs = 0; cs < 4; ++cs) {
            bf16x8 wf = *(const bf16x8*)(Wm + (dt * 16 + col) * 128 + cs * 32 + quad * 8);
            acc = MFMA16(wf, bx[cs], acc);
        }
        if (role < 2) {
            bf16* Ot = (role == 0) ? Qt : Kt;
            union { ushort4 u4; bf16 h[4]; } pk;
            #pragma unroll
            for (int r = 0; r < 4; ++r) pk.h[r] = (bf16)acc[r];
            *(ushort4*)(Ot + ((size_t)b * N_ + n) * C_ + dt * 16 + quad * 4) = pk.u4;
        } else {
            #pragma unroll
            for (int r = 0; r < 4; ++r)
                vt[(dt * 16 + quad * 4 + r) * 72 + nl] = (bf16)acc[r];
        }
    }
    __syncthreads();          // B2: vt complete

    // ---- V store: coalesced 16B rows from vt ----
    for (int s = t; s < 1024; s += 768) {
        int c = s >> 3, off = s & 7;
        *(uint4*)(Vt + ((size_t)b * C_ + c) * (size_t)M_ + n0 + off * 8) =
            *(const uint4*)&vt[c * 72 + off * 8];
    }
}

// ===========================================================================
// Kernel 2 (v3): 64-query blocks, 8 waves = 2 q-groups x 4 key-groups,
// DOUBLE-BUFFERED K/V (128 KB LDS), grid 256 = 1 block/CU.
// Per chunk: ONE aged vmcnt(0) + ONE barrier; stage(ch+1) issued right after
// the barrier, waited a full chunk body later (T3/T4 invariant). Per-wave
// math (swapped QK, in-register softmax transpose, PV slot map) is identical
// to the round-3 verified kernel. L2 demand per XCD halves vs round 3.
// ===========================================================================
__global__ __launch_bounds__(512) void attn_kernel(
    const bf16* __restrict__ Qt, const bf16* __restrict__ Kt,
    const bf16* __restrict__ Vt, const float* __restrict__ x1,
    float* __restrict__ out) {
    __shared__ __align__(16) char smem[132096];
    // kb[buf] = smem + buf*32768          [128 key][16 slots, slot^=key&15]
    // vb[buf] = smem + 65536 + buf*32768  [128 c ][16 slots, slot^=c&15]

    const int t = threadIdx.x;
    const int w = t >> 6;
    const int lane = t & 63;
    const int col = lane & 31;
    const int hi = lane >> 5;
    const int kg = w & 3;            // key-group (32 keys of 128-key chunk)
    const int qg = w >> 2;           // query-group (32 of the 64 queries)

    // XCD-aware decode: batch -> XCD pair (K+V of one batch L2-resident)
    const int g0 = blockIdx.x;
    const int xcd = g0 & 7;
    const int b = xcd >> 1;
    const int qt = (xcd & 1) + ((g0 >> 3) << 1);   // 64 q-tiles of 64
    const int n0 = qt * 64;

    const float KS = 0.12752107168406815f;  // log2(e)/sqrt(128)

    const bf16* Kbase = Kt + (size_t)b * M_ * C_;
    const bf16* Vbase = Vt + (size_t)b * C_ * M_;

    // Q fragments (B-operand of swapped QK): lane col = query, k = hi*8+j
    bf16x8 qf[8];
    {
        const bf16* Qb = Qt + ((size_t)b * N_ + n0 + qg * 32 + col) * C_ + hi * 8;
        #pragma unroll
        for (int cs = 0; cs < 8; ++cs)
            qf[cs] = *(const bf16x8*)(Qb + cs * 16);
    }

    f32x16 oacc[4];
    #pragma unroll
    for (int i = 0; i < 4; ++i)
        #pragma unroll
        for (int j = 0; j < 16; ++j) oacc[i][j] = 0.f;
    float lacc = 0.f;

    const int key_l = (kg << 5) + col;
    const int kxor = (key_l & 15) << 4;

    // staging: 2048 16B-segs per tile; wave w covers segs [w*256, w*256+256)
    auto stageK = [&](int m0, char* dst) {
        #pragma unroll
        for (int i = 0; i < 4; ++i) {
            int g = ((w << 2) + i) * 64 + lane;
            int key = g >> 4;
            int sp = (g & 15) ^ (key & 15);   // inverse-swizzled SOURCE
            gll16(Kbase + (size_t)(m0 + key) * C_ + sp * 8,
                  (bf16*)dst + ((w << 2) + i) * 512);
        }
    };
    auto stageV = [&](int m0, char* dst) {
        #pragma unroll
        for (int i = 0; i < 4; ++i) {
            int g = ((w << 2) + i) * 64 + lane;
            int c = g >> 4;
            int sp = (g & 15) ^ (c & 15);
            gll16(Vbase + (size_t)c * M_ + m0 + sp * 8,
                  (bf16*)dst + ((w << 2) + i) * 512);
        }
    };

    stageK(0, smem);
    stageV(0, smem + 65536);

    int buf = 0;
    for (int ch = 0; ch < 32; ++ch) {
        // my stage(ch) loads landed (issued a full chunk body ago)
        asm volatile("s_waitcnt vmcnt(0)" ::: "memory");
        __builtin_amdgcn_sched_barrier(0);
        __builtin_amdgcn_s_barrier();   // everyone's cur landed; prev reads retired

        if (ch < 31) {
            stageK((ch + 1) << 7, smem + ((buf ^ 1) << 15));
            stageV((ch + 1) << 7, smem + 65536 + ((buf ^ 1) << 15));
        }

        const char* kbp = smem + (buf << 15) + key_l * 256;

        // ---- S^T = K Q : D lane = query, regs = keys (swapped operands) ----
        f32x16 s0a, s1a;
        #pragma unroll
        for (int j = 0; j < 16; ++j) { s0a[j] = 0.f; s1a[j] = 0.f; }
        __builtin_amdgcn_s_setprio(1);
        #pragma unroll
        for (int cs = 0; cs < 4; ++cs) {
            bf16x8 kf = *(const bf16x8*)(kbp + ((((cs << 1) + hi) << 4) ^ kxor));
            s0a = MFMA32(kf, qf[cs], s0a);
        }
        #pragma unroll
        for (int cs = 4; cs < 8; ++cs) {
            bf16x8 kf = *(const bf16x8*)(kbp + ((((cs << 1) + hi) << 4) ^ kxor));
            s1a = MFMA32(kf, qf[cs], s1a);
        }
        __builtin_amdgcn_s_setprio(0);

        // ---- P = exp2(S*KS); lane(q=col,hi) holds keys (r&3)+8(r>>2)+4hi ----
        float p[16];
        #pragma unroll
        for (int r = 0; r < 16; ++r) {
            float e = fminf((s0a[r] + s1a[r]) * KS, 60.f);
            p[r] = __builtin_amdgcn_exp2f(e);
        }
        {
            float s01 = (p[0] + p[1]) + (p[2] + p[3]);
            float s23 = (p[4] + p[5]) + (p[6] + p[7]);
            float s45 = (p[8] + p[9]) + (p[10] + p[11]);
            float s67 = (p[12] + p[13]) + (p[14] + p[15]);
            lacc += (s01 + s23) + (s45 + s67);
        }
        // pack to bf16 pairs: W0..W7; cross-hi exchange via shfl_xor(32)
        unsigned W0 = cvtpk(p[0], p[1]),  W1 = cvtpk(p[2], p[3]);
        unsigned W2 = cvtpk(p[4], p[5]),  W3 = cvtpk(p[6], p[7]);
        unsigned W4 = cvtpk(p[8], p[9]),  W5 = cvtpk(p[10], p[11]);
        unsigned W6 = cvtpk(p[12], p[13]), W7 = cvtpk(p[14], p[15]);
        unsigned X0 = hi ? W0 : W2, X1 = hi ? W1 : W3;
        unsigned Y0 = hi ? W4 : W6, Y1 = hi ? W5 : W7;
        X0 = __shfl_xor(X0, 32, 64);  X1 = __shfl_xor(X1, 32, 64);
        Y0 = __shfl_xor(Y0, 32, 64);  Y1 = __shfl_xor(Y1, 32, 64);
        uint4 u0, u1;
        u0.x = hi ? X0 : W0;  u0.y = hi ? X1 : W1;
        u0.z = hi ? W2 : X0;  u0.w = hi ? W3 : X1;
        u1.x = hi ? Y0 : W4;  u1.y = hi ? Y1 : W5;
        u1.z = hi ? W6 : Y0;  u1.w = hi ? W7 : Y1;
        bf16x8 af0 = __builtin_bit_cast(bf16x8, u0);   // keys hi*8   .. +7
        bf16x8 af1 = __builtin_bit_cast(bf16x8, u1);   // keys 16+hi*8.. +7

        // ---- O += P V^T ----
        const char* vbB = smem + 65536 + (buf << 15);
        __builtin_amdgcn_s_setprio(1);
        #pragma unroll
        for (int ct = 0; ct < 4; ++ct) {
            int c = (ct << 5) + col;
            const char* vbp = vbB + c * 256;
            int vxor = (c & 15) << 4;
            bf16x8 vf0 = *(const bf16x8*)(vbp + ((((kg << 2) + hi) << 4) ^ vxor));
            bf16x8 vf1 = *(const bf16x8*)(vbp + ((((kg << 2) + 2 + hi) << 4) ^ vxor));
            oacc[ct] = MFMA32(af0, vf0, oacc[ct]);
            oacc[ct] = MFMA32(af1, vf1, oacc[ct]);
        }
        __builtin_amdgcn_s_setprio(0);

        // my ds_reads of cur retired before next iteration's barrier
        asm volatile("s_waitcnt lgkmcnt(0)" ::: "memory");
        __builtin_amdgcn_sched_barrier(0);
        buf ^= 1;
    }

    __builtin_amdgcn_s_barrier();   // all LDS reads retired; reuse smem

    // ---- cross-wave merge of key-group partials ----
    float* obuf = (float*)smem;                 // [4 kg][64 q][128 c]  128 KB
    float* lps  = (float*)(smem + 131072);      // [4 kg][64 q]

    lacc += __shfl_xor(lacc, 32, 64);           // + other hi-half's 16 keys
    if (hi == 0) lps[(kg << 6) + (qg << 5) + col] = lacc;

    #pragma unroll
    for (int ct = 0; ct < 4; ++ct)
        #pragma unroll
        for (int r = 0; r < 16; ++r) {
            int q = (r & 3) + ((r >> 2) << 3) + (hi << 2);
            obuf[kg * 8192 + ((qg << 5) + q) * 128 + (ct << 5) + col] = oacc[ct][r];
        }
    __syncthreads();

    const int c2 = lane << 1;                   // 2 channels per lane
    #pragma unroll
    for (int j = 0; j < 8; ++j) {
        int q = (w << 3) + j;                   // wave w finalizes queries w*8..+7
        float s0 = 0.f, s1 = 0.f;
        #pragma unroll
        for (int pp = 0; pp < 4; ++pp) {
            float2 v = *(const float2*)&obuf[pp * 8192 + q * 128 + c2];
            s0 += v.x; s1 += v.y;
        }
        float lsum = lps[q] + lps[64 + q] + lps[128 + q] + lps[192 + q];
        float linv = 1.0f / lsum;
        int n = n0 + q;
        float o0 = s0 * linv + x1[((size_t)b * C_ + c2) * N_ + n];
        float o1 = s1 * linv + x1[((size_t)b * C_ + c2 + 1) * N_ + n];
        *(float2*)&out[((size_t)b * N_ + n) * C_ + c2] = make_float2(o0, o1);
    }
}

// ---------------------------------------------------------------------------
extern "C" void kernel_launch(void* const* d_in, const int* in_sizes, int n_in,
                              void* d_out, int out_size, void* d_ws, size_t ws_size,
                              hipStream_t stream) {
    const float* x1   = (const float*)d_in[0];
    const float* p1   = (const float*)d_in[1];
    const float* x2   = (const float*)d_in[2];
    const float* p2   = (const float*)d_in[3];
    const float* Wq   = (const float*)d_in[4];
    const float* Wk   = (const float*)d_in[5];
    const float* Wv   = (const float*)d_in[6];
    const float* Wpos = (const float*)d_in[7];
    float* out = (float*)d_out;

    bf16* Qt = (bf16*)d_ws;                 // [B][N][C]
    bf16* Kt = Qt + (size_t)B_ * N_ * C_;   // [B][M][C]
    bf16* Vt = Kt + (size_t)B_ * M_ * C_;   // [B][C][M]

    // bf16 W parked in the head of out (96 KB of 8 MB); proj reads it, then
    // attn fully overwrites out.
    bf16* Wb = (bf16*)d_out;

    wcvt_kernel<<<dim3(48), dim3(256), 0, stream>>>(Wq, Wk, Wv, Wb);
    proj_kernel<<<dim3(64, B_), dim3(768), 0, stream>>>(
        x1, p1, x2, p2, Wb, Wpos, Qt, Kt, Vt);
    attn_kernel<<<dim3(256), dim3(512), 0, stream>>>(Qt, Kt, Vt, x1, out);
}

// Round 5
// 145.170 us; speedup vs baseline: 1.8103x; 1.0080x over previous
//
#include <hip/hip_runtime.h>
#include <hip/hip_bf16.h>

#define B_ 4
#define C_ 128
#define N_ 4096
#define M_ 4096

typedef __bf16 bf16;
typedef __bf16 bf16x8 __attribute__((ext_vector_type(8)));
typedef float f32x4 __attribute__((ext_vector_type(4)));
typedef float f32x16 __attribute__((ext_vector_type(16)));

#define MFMA16(a, b, c) __builtin_amdgcn_mfma_f32_16x16x32_bf16(a, b, c, 0, 0, 0)
#define MFMA32(a, b, c) __builtin_amdgcn_mfma_f32_32x32x16_bf16(a, b, c, 0, 0, 0)

// async 16B global -> LDS (dest = wave-uniform base + lane*16)
__device__ inline void gll16(const bf16* g, bf16* l) {
    __builtin_amdgcn_global_load_lds(
        (const __attribute__((address_space(1))) void*)g,
        (__attribute__((address_space(3))) void*)l, 16, 0, 0);
}

// v_cvt_pk_bf16_f32: pack two f32 -> u32 of 2 bf16 (lo = a, hi = b)
__device__ inline unsigned cvtpk(float a, float b) {
    unsigned r;
    asm("v_cvt_pk_bf16_f32 %0, %1, %2" : "=v"(r) : "v"(a), "v"(b));
    return r;
}

// ===========================================================================
// Kernel 0: one-shot W f32->bf16 conversion (parked in head of d_out, which
// attn fully overwrites later).
// ===========================================================================
__global__ __launch_bounds__(256) void wcvt_kernel(
    const float* __restrict__ Wq, const float* __restrict__ Wk,
    const float* __restrict__ Wv, bf16* __restrict__ Wb) {
    int i = (blockIdx.x * 256 + threadIdx.x) * 4;        // 49152 elements total
    const float* src = (i < 16384) ? Wq : (i < 32768) ? Wk : Wv;
    int off = i & 16383;
    float4 v = *(const float4*)(src + off);
    union { ushort4 u4; bf16 h[4]; } pk;
    pk.h[0] = (bf16)v.x; pk.h[1] = (bf16)v.y;
    pk.h[2] = (bf16)v.z; pk.h[3] = (bf16)v.w;
    *(ushort4*)(Wb + i) = pk.u4;
}

// ===========================================================================
// Kernel 1: fused projections — REVERTED to the round-3 version (direct V
// stores; the round-4 LDS-transpose V epilogue regressed ~4 us: 2 extra
// barriers in a 12-wave block vs scattered 2B stores that L2 absorbs).
// ===========================================================================
__global__ __launch_bounds__(768) void proj_kernel(
    const float* __restrict__ x1, const float* __restrict__ p1,
    const float* __restrict__ x2, const float* __restrict__ p2,
    const bf16* __restrict__ Wb, const float* __restrict__ Wpos,
    bf16* __restrict__ Qt, bf16* __restrict__ Kt, bf16* __restrict__ Vt) {
    __shared__ __align__(16) bf16 xp1[64 * 136];   // x1 + pos   17.4 KB
    __shared__ __align__(16) bf16 xp2[64 * 136];   // x2 + pos
    __shared__ __align__(16) bf16 xr2[64 * 136];   // x2 raw
    __shared__ float pp1[3 * 64], pp2[3 * 64], wls[384];

    const int t = threadIdx.x;
    const int b = blockIdx.y;
    const int n0 = blockIdx.x * 64;

    // ---- phase A: stage p1/p2/Wpos ----
    if (t < 48) {
        int k3 = t / 16, i4 = (t & 15) * 4;
        *(float4*)&pp1[k3 * 64 + i4] = *(const float4*)(p1 + ((size_t)b * 3 + k3) * N_ + n0 + i4);
    } else if (t < 96) {
        int tt = t - 48;
        int k3 = tt / 16, i4 = (tt & 15) * 4;
        *(float4*)&pp2[k3 * 64 + i4] = *(const float4*)(p2 + ((size_t)b * 3 + k3) * N_ + n0 + i4);
    } else if (t < 192) {
        int i4 = (t - 96) * 4;
        *(float4*)&wls[i4] = *(const float4*)(Wpos + i4);
    }
    __syncthreads();

    // ---- phase B: stage x tiles, fold pos, transpose to [n][c] bf16 ----
    for (int s = t; s < 2048; s += 768) {
        int c = s >> 4, n4 = (s & 15) * 4;
        float4 xv = *(const float4*)(x1 + ((size_t)b * C_ + c) * N_ + n0 + n4);
        float w0 = wls[c * 3 + 0], w1 = wls[c * 3 + 1], w2 = wls[c * 3 + 2];
        const float* xa = &xv.x;
        #pragma unroll
        for (int j = 0; j < 4; ++j) {
            float pos = w0 * pp1[n4 + j] + w1 * pp1[64 + n4 + j] + w2 * pp1[128 + n4 + j];
            xp1[(n4 + j) * 136 + c] = (bf16)(xa[j] + pos);
        }
    }
    for (int s = t; s < 2048; s += 768) {
        int c = s >> 4, n4 = (s & 15) * 4;
        float4 xv = *(const float4*)(x2 + ((size_t)b * C_ + c) * N_ + n0 + n4);
        float w0 = wls[c * 3 + 0], w1 = wls[c * 3 + 1], w2 = wls[c * 3 + 2];
        const float* xa = &xv.x;
        #pragma unroll
        for (int j = 0; j < 4; ++j) {
            float pos = w0 * pp2[n4 + j] + w1 * pp2[64 + n4 + j] + w2 * pp2[128 + n4 + j];
            xp2[(n4 + j) * 136 + c] = (bf16)(xa[j] + pos);
            xr2[(n4 + j) * 136 + c] = (bf16)xa[j];
        }
    }
    __syncthreads();

    // ---- phase C: MFMA per role ----
    const int w = t >> 6;
    const int lane = t & 63;
    const int col = lane & 15, quad = lane >> 4;
    const int role = w >> 2, band = w & 3;
    const int nl = band * 16 + col;
    const int n = n0 + nl;

    const bf16* src = (role == 0) ? xp1 : (role == 1) ? xp2 : xr2;
    const bf16* Wm = Wb + role * 16384;   // bf16 W, same [row][col] layout

    bf16x8 bx[4];
    #pragma unroll
    for (int cs = 0; cs < 4; ++cs)
        bx[cs] = *(const bf16x8*)&src[nl * 136 + cs * 32 + quad * 8];

    #pragma unroll
    for (int dt = 0; dt < 8; ++dt) {
        f32x4 acc = {0.f, 0.f, 0.f, 0.f};
        #pragma unroll
        for (int cs = 0; cs < 4; ++cs) {
            bf16x8 wf = *(const bf16x8*)(Wm + (dt * 16 + col) * 128 + cs * 32 + quad * 8);
            acc = MFMA16(wf, bx[cs], acc);
        }
        if (role < 2) {
            bf16* Ot = (role == 0) ? Qt : Kt;
            union { ushort4 u4; bf16 h[4]; } pk;
            #pragma unroll
            for (int r = 0; r < 4; ++r) pk.h[r] = (bf16)acc[r];
            *(ushort4*)(Ot + ((size_t)b * N_ + n) * C_ + dt * 16 + quad * 4) = pk.u4;
        } else {
            #pragma unroll
            for (int r = 0; r < 4; ++r)
                Vt[((size_t)b * C_ + dt * 16 + quad * 4 + r) * (size_t)M_ + n] = (bf16)acc[r];
        }
    }
}

// ===========================================================================
// Kernel 2 (v4): deep pipeline. K TRIPLE-buffered, V DOUBLE-buffered
// (160 KB LDS exactly). Issue order per body j: [wait vmcnt(4)] [barrier]
// [stageV(j+1)] [stageK(j+2)] [QK] [softmax] [PV]. FIFO: ...V(j),K(j+1),
// V(j+1),K(j+2)... -> vmcnt(4) drains exactly K(j),V(j), keeps K(j+1)
// flying. K age = 2 bodies, V age ~1.3 bodies, NO full vmcnt(0) drain in
// the loop, ONE barrier per body. Buffer disjointness makes the single
// barrier race-free (a leading wave writes kb[(j+2)%3]/vb[(j+1)&1], never
// a buffer body-j readers use). Math identical to the round-3/4 verified
// kernel (swapped QK, in-register softmax transpose, PV slot map).
// ===========================================================================
__global__ __launch_bounds__(512) void attn_kernel(
    const bf16* __restrict__ Qt, const bf16* __restrict__ Kt,
    const bf16* __restrict__ Vt, const float* __restrict__ x1,
    float* __restrict__ out) {
    __shared__ __align__(16) char smem[163840];
    // kb bufs: 0 / 32768 / 65536   [128 key][16 slots, slot^=key&15]
    // vb bufs: 98304 / 131072      [128 c ][16 slots, slot^=c&15]

    const int t = threadIdx.x;
    const int w = t >> 6;
    const int lane = t & 63;
    const int col = lane & 31;
    const int hi = lane >> 5;
    const int kg = w & 3;            // key-group (32 keys of 128-key chunk)
    const int qg = w >> 2;           // query-group (32 of the 64 queries)

    // XCD-aware decode: batch -> XCD pair (K+V of one batch L2-resident)
    const int g0 = blockIdx.x;
    const int xcd = g0 & 7;
    const int b = xcd >> 1;
    const int qt = (xcd & 1) + ((g0 >> 3) << 1);   // 64 q-tiles of 64
    const int n0 = qt * 64;

    const float KS = 0.12752107168406815f;  // log2(e)/sqrt(128)

    const bf16* Kbase = Kt + (size_t)b * M_ * C_;
    const bf16* Vbase = Vt + (size_t)b * C_ * M_;

    // Q fragments (B-operand of swapped QK): lane col = query, k = hi*8+j
    bf16x8 qf[8];
    {
        const bf16* Qb = Qt + ((size_t)b * N_ + n0 + qg * 32 + col) * C_ + hi * 8;
        #pragma unroll
        for (int cs = 0; cs < 8; ++cs)
            qf[cs] = *(const bf16x8*)(Qb + cs * 16);
    }

    f32x16 oacc[4];
    #pragma unroll
    for (int i = 0; i < 4; ++i)
        #pragma unroll
        for (int j = 0; j < 16; ++j) oacc[i][j] = 0.f;
    float lacc = 0.f;

    const int key_l = (kg << 5) + col;
    const int kxor = (key_l & 15) << 4;

    // staging: 2048 16B-segs per tile; wave w covers segs [w*256, w*256+256)
    auto stageK = [&](int m0, int dstOff) {
        #pragma unroll
        for (int i = 0; i < 4; ++i) {
            int g = ((w << 2) + i) * 64 + lane;
            int key = g >> 4;
            int sp = (g & 15) ^ (key & 15);   // inverse-swizzled SOURCE
            gll16(Kbase + (size_t)(m0 + key) * C_ + sp * 8,
                  (bf16*)(smem + dstOff) + ((w << 2) + i) * 512);
        }
    };
    auto stageV = [&](int m0, int dstOff) {
        #pragma unroll
        for (int i = 0; i < 4; ++i) {
            int g = ((w << 2) + i) * 64 + lane;
            int c = g >> 4;
            int sp = (g & 15) ^ (c & 15);
            gll16(Vbase + (size_t)c * M_ + m0 + sp * 8,
                  (bf16*)(smem + dstOff) + ((w << 2) + i) * 512);
        }
    };

    // prologue: FIFO = K0(4), V0(4), K1(4)
    stageK(0, 0);
    stageV(0, 98304);
    stageK(128, 32768);

    int koR = 0;          // K read buf  (j%3)     * 32768
    int koW = 65536;      // K write buf ((j+2)%3) * 32768
    int voR = 98304;      // V read buf 98304 + (j&1)*32768

    for (int ch = 0; ch < 32; ++ch) {
        // drain K(ch),V(ch); keep K(ch+1) in flight (FIFO order guarantees it)
        if (ch < 31) asm volatile("s_waitcnt vmcnt(4)" ::: "memory");
        else         asm volatile("s_waitcnt vmcnt(0)" ::: "memory");
        __builtin_amdgcn_sched_barrier(0);
        __builtin_amdgcn_s_barrier();          // publishes K(ch) and V(ch)
        __builtin_amdgcn_sched_barrier(0);

        if (ch < 31) stageV((ch + 1) << 7, voR ^ 32768);
        if (ch < 30) stageK((ch + 2) << 7, koW);

        const char* kbp = smem + koR + key_l * 256;

        // ---- S^T = K Q : D lane = query, regs = keys (swapped operands) ----
        f32x16 s0a, s1a;
        #pragma unroll
        for (int j = 0; j < 16; ++j) { s0a[j] = 0.f; s1a[j] = 0.f; }
        __builtin_amdgcn_s_setprio(1);
        #pragma unroll
        for (int cs = 0; cs < 4; ++cs) {
            bf16x8 kf = *(const bf16x8*)(kbp + ((((cs << 1) + hi) << 4) ^ kxor));
            s0a = MFMA32(kf, qf[cs], s0a);
        }
        #pragma unroll
        for (int cs = 4; cs < 8; ++cs) {
            bf16x8 kf = *(const bf16x8*)(kbp + ((((cs << 1) + hi) << 4) ^ kxor));
            s1a = MFMA32(kf, qf[cs], s1a);
        }
        __builtin_amdgcn_s_setprio(0);

        // ---- P = exp2(S*KS); lane(q=col,hi) holds keys (r&3)+8(r>>2)+4hi ----
        float p[16];
        #pragma unroll
        for (int r = 0; r < 16; ++r) {
            float e = fminf((s0a[r] + s1a[r]) * KS, 60.f);
            p[r] = __builtin_amdgcn_exp2f(e);
        }
        {
            float s01 = (p[0] + p[1]) + (p[2] + p[3]);
            float s23 = (p[4] + p[5]) + (p[6] + p[7]);
            float s45 = (p[8] + p[9]) + (p[10] + p[11]);
            float s67 = (p[12] + p[13]) + (p[14] + p[15]);
            lacc += (s01 + s23) + (s45 + s67);
        }
        // pack to bf16 pairs: W0..W7; cross-hi exchange via shfl_xor(32)
        unsigned W0 = cvtpk(p[0], p[1]),  W1 = cvtpk(p[2], p[3]);
        unsigned W2 = cvtpk(p[4], p[5]),  W3 = cvtpk(p[6], p[7]);
        unsigned W4 = cvtpk(p[8], p[9]),  W5 = cvtpk(p[10], p[11]);
        unsigned W6 = cvtpk(p[12], p[13]), W7 = cvtpk(p[14], p[15]);
        unsigned X0 = hi ? W0 : W2, X1 = hi ? W1 : W3;
        unsigned Y0 = hi ? W4 : W6, Y1 = hi ? W5 : W7;
        X0 = __shfl_xor(X0, 32, 64);  X1 = __shfl_xor(X1, 32, 64);
        Y0 = __shfl_xor(Y0, 32, 64);  Y1 = __shfl_xor(Y1, 32, 64);
        uint4 u0, u1;
        u0.x = hi ? X0 : W0;  u0.y = hi ? X1 : W1;
        u0.z = hi ? W2 : X0;  u0.w = hi ? W3 : X1;
        u1.x = hi ? Y0 : W4;  u1.y = hi ? Y1 : W5;
        u1.z = hi ? W6 : Y0;  u1.w = hi ? W7 : Y1;
        bf16x8 af0 = __builtin_bit_cast(bf16x8, u0);   // keys hi*8   .. +7
        bf16x8 af1 = __builtin_bit_cast(bf16x8, u1);   // keys 16+hi*8.. +7

        // ---- O += P V^T ----
        const char* vbB = smem + voR;
        __builtin_amdgcn_s_setprio(1);
        #pragma unroll
        for (int ct = 0; ct < 4; ++ct) {
            int c = (ct << 5) + col;
            const char* vbp = vbB + c * 256;
            int vxor = (c & 15) << 4;
            bf16x8 vf0 = *(const bf16x8*)(vbp + ((((kg << 2) + hi) << 4) ^ vxor));
            bf16x8 vf1 = *(const bf16x8*)(vbp + ((((kg << 2) + 2 + hi) << 4) ^ vxor));
            oacc[ct] = MFMA32(af0, vf0, oacc[ct]);
            oacc[ct] = MFMA32(af1, vf1, oacc[ct]);
        }
        __builtin_amdgcn_s_setprio(0);

        // rotate buffers (wave-uniform scalar math)
        koR += 32768; if (koR == 98304) koR = 0;
        koW += 32768; if (koW == 98304) koW = 0;
        voR ^= 32768;
    }

    // all ds_reads were MFMA-consumed (retired); publish before smem reuse
    asm volatile("s_waitcnt lgkmcnt(0)" ::: "memory");
    __builtin_amdgcn_sched_barrier(0);
    __builtin_amdgcn_s_barrier();

    // ---- cross-wave merge of key-group partials ----
    float* obuf = (float*)smem;                 // [4 kg][64 q][128 c]  128 KB
    float* lps  = (float*)(smem + 131072);      // [4 kg][64 q]

    lacc += __shfl_xor(lacc, 32, 64);           // + other hi-half's 16 keys
    if (hi == 0) lps[(kg << 6) + (qg << 5) + col] = lacc;

    #pragma unroll
    for (int ct = 0; ct < 4; ++ct)
        #pragma unroll
        for (int r = 0; r < 16; ++r) {
            int q = (r & 3) + ((r >> 2) << 3) + (hi << 2);
            obuf[kg * 8192 + ((qg << 5) + q) * 128 + (ct << 5) + col] = oacc[ct][r];
        }
    __syncthreads();

    const int c2 = lane << 1;                   // 2 channels per lane
    #pragma unroll
    for (int j = 0; j < 8; ++j) {
        int q = (w << 3) + j;                   // wave w finalizes queries w*8..+7
        float s0 = 0.f, s1 = 0.f;
        #pragma unroll
        for (int pp = 0; pp < 4; ++pp) {
            float2 v = *(const float2*)&obuf[pp * 8192 + q * 128 + c2];
            s0 += v.x; s1 += v.y;
        }
        float lsum = lps[q] + lps[64 + q] + lps[128 + q] + lps[192 + q];
        float linv = 1.0f / lsum;
        int n = n0 + q;
        float o0 = s0 * linv + x1[((size_t)b * C_ + c2) * N_ + n];
        float o1 = s1 * linv + x1[((size_t)b * C_ + c2 + 1) * N_ + n];
        *(float2*)&out[((size_t)b * N_ + n) * C_ + c2] = make_float2(o0, o1);
    }
}

// ---------------------------------------------------------------------------
extern "C" void kernel_launch(void* const* d_in, const int* in_sizes, int n_in,
                              void* d_out, int out_size, void* d_ws, size_t ws_size,
                              hipStream_t stream) {
    const float* x1   = (const float*)d_in[0];
    const float* p1   = (const float*)d_in[1];
    const float* x2   = (const float*)d_in[2];
    const float* p2   = (const float*)d_in[3];
    const float* Wq   = (const float*)d_in[4];
    const float* Wk   = (const float*)d_in[5];
    const float* Wv   = (const float*)d_in[6];
    const float* Wpos = (const float*)d_in[7];
    float* out = (float*)d_out;

    bf16* Qt = (bf16*)d_ws;                 // [B][N][C]
    bf16* Kt = Qt + (size_t)B_ * N_ * C_;   // [B][M][C]
    bf16* Vt = Kt + (size_t)B_ * M_ * C_;   // [B][C][M]

    // bf16 W parked in the head of out (96 KB of 8 MB); proj reads it, then
    // attn fully overwrites out.
    bf16* Wb = (bf16*)d_out;

    wcvt_kernel<<<dim3(48), dim3(256), 0, stream>>>(Wq, Wk, Wv, Wb);
    proj_kernel<<<dim3(64, B_), dim3(768), 0, stream>>>(
        x1, p1, x2, p2, Wb, Wpos, Qt, Kt, Vt);
    attn_kernel<<<dim3(256), dim3(512), 0, stream>>>(Qt, Kt, Vt, x1, out);
}

// Round 6
// 143.875 us; speedup vs baseline: 1.8266x; 1.0090x over previous
//
#include <hip/hip_runtime.h>
#include <hip/hip_bf16.h>

#define B_ 4
#define C_ 128
#define N_ 4096
#define M_ 4096

typedef __bf16 bf16;
typedef __bf16 bf16x8 __attribute__((ext_vector_type(8)));
typedef float f32x4 __attribute__((ext_vector_type(4)));
typedef float f32x16 __attribute__((ext_vector_type(16)));

#define MFMA16(a, b, c) __builtin_amdgcn_mfma_f32_16x16x32_bf16(a, b, c, 0, 0, 0)
#define MFMA32(a, b, c) __builtin_amdgcn_mfma_f32_32x32x16_bf16(a, b, c, 0, 0, 0)

// async 16B global -> LDS (dest = wave-uniform base + lane*16)
__device__ inline void gll16(const bf16* g, bf16* l) {
    __builtin_amdgcn_global_load_lds(
        (const __attribute__((address_space(1))) void*)g,
        (__attribute__((address_space(3))) void*)l, 16, 0, 0);
}

// v_cvt_pk_bf16_f32: pack two f32 -> u32 of 2 bf16 (lo = a, hi = b)
__device__ inline unsigned cvtpk(float a, float b) {
    unsigned r;
    asm("v_cvt_pk_bf16_f32 %0, %1, %2" : "=v"(r) : "v"(a), "v"(b));
    return r;
}

// ===========================================================================
// Kernel 0: one-shot W f32->bf16 conversion (parked in head of d_out, which
// attn fully overwrites later).
// ===========================================================================
__global__ __launch_bounds__(256) void wcvt_kernel(
    const float* __restrict__ Wq, const float* __restrict__ Wk,
    const float* __restrict__ Wv, bf16* __restrict__ Wb) {
    int i = (blockIdx.x * 256 + threadIdx.x) * 4;        // 49152 elements total
    const float* src = (i < 16384) ? Wq : (i < 32768) ? Wk : Wv;
    int off = i & 16383;
    float4 v = *(const float4*)(src + off);
    union { ushort4 u4; bf16 h[4]; } pk;
    pk.h[0] = (bf16)v.x; pk.h[1] = (bf16)v.y;
    pk.h[2] = (bf16)v.z; pk.h[3] = (bf16)v.w;
    *(ushort4*)(Wb + i) = pk.u4;
}

// ===========================================================================
// Kernel 1: fused projections (unchanged — round-3 verified version).
// ===========================================================================
__global__ __launch_bounds__(768) void proj_kernel(
    const float* __restrict__ x1, const float* __restrict__ p1,
    const float* __restrict__ x2, const float* __restrict__ p2,
    const bf16* __restrict__ Wb, const float* __restrict__ Wpos,
    bf16* __restrict__ Qt, bf16* __restrict__ Kt, bf16* __restrict__ Vt) {
    __shared__ __align__(16) bf16 xp1[64 * 136];   // x1 + pos   17.4 KB
    __shared__ __align__(16) bf16 xp2[64 * 136];   // x2 + pos
    __shared__ __align__(16) bf16 xr2[64 * 136];   // x2 raw
    __shared__ float pp1[3 * 64], pp2[3 * 64], wls[384];

    const int t = threadIdx.x;
    const int b = blockIdx.y;
    const int n0 = blockIdx.x * 64;

    // ---- phase A: stage p1/p2/Wpos ----
    if (t < 48) {
        int k3 = t / 16, i4 = (t & 15) * 4;
        *(float4*)&pp1[k3 * 64 + i4] = *(const float4*)(p1 + ((size_t)b * 3 + k3) * N_ + n0 + i4);
    } else if (t < 96) {
        int tt = t - 48;
        int k3 = tt / 16, i4 = (tt & 15) * 4;
        *(float4*)&pp2[k3 * 64 + i4] = *(const float4*)(p2 + ((size_t)b * 3 + k3) * N_ + n0 + i4);
    } else if (t < 192) {
        int i4 = (t - 96) * 4;
        *(float4*)&wls[i4] = *(const float4*)(Wpos + i4);
    }
    __syncthreads();

    // ---- phase B: stage x tiles, fold pos, transpose to [n][c] bf16 ----
    for (int s = t; s < 2048; s += 768) {
        int c = s >> 4, n4 = (s & 15) * 4;
        float4 xv = *(const float4*)(x1 + ((size_t)b * C_ + c) * N_ + n0 + n4);
        float w0 = wls[c * 3 + 0], w1 = wls[c * 3 + 1], w2 = wls[c * 3 + 2];
        const float* xa = &xv.x;
        #pragma unroll
        for (int j = 0; j < 4; ++j) {
            float pos = w0 * pp1[n4 + j] + w1 * pp1[64 + n4 + j] + w2 * pp1[128 + n4 + j];
            xp1[(n4 + j) * 136 + c] = (bf16)(xa[j] + pos);
        }
    }
    for (int s = t; s < 2048; s += 768) {
        int c = s >> 4, n4 = (s & 15) * 4;
        float4 xv = *(const float4*)(x2 + ((size_t)b * C_ + c) * N_ + n0 + n4);
        float w0 = wls[c * 3 + 0], w1 = wls[c * 3 + 1], w2 = wls[c * 3 + 2];
        const float* xa = &xv.x;
        #pragma unroll
        for (int j = 0; j < 4; ++j) {
            float pos = w0 * pp2[n4 + j] + w1 * pp2[64 + n4 + j] + w2 * pp2[128 + n4 + j];
            xp2[(n4 + j) * 136 + c] = (bf16)(xa[j] + pos);
            xr2[(n4 + j) * 136 + c] = (bf16)xa[j];
        }
    }
    __syncthreads();

    // ---- phase C: MFMA per role ----
    const int w = t >> 6;
    const int lane = t & 63;
    const int col = lane & 15, quad = lane >> 4;
    const int role = w >> 2, band = w & 3;
    const int nl = band * 16 + col;
    const int n = n0 + nl;

    const bf16* src = (role == 0) ? xp1 : (role == 1) ? xp2 : xr2;
    const bf16* Wm = Wb + role * 16384;   // bf16 W, same [row][col] layout

    bf16x8 bx[4];
    #pragma unroll
    for (int cs = 0; cs < 4; ++cs)
        bx[cs] = *(const bf16x8*)&src[nl * 136 + cs * 32 + quad * 8];

    #pragma unroll
    for (int dt = 0; dt < 8; ++dt) {
        f32x4 acc = {0.f, 0.f, 0.f, 0.f};
        #pragma unroll
        for (int cs = 0; cs < 4; ++cs) {
            bf16x8 wf = *(const bf16x8*)(Wm + (dt * 16 + col) * 128 + cs * 32 + quad * 8);
            acc = MFMA16(wf, bx[cs], acc);
        }
        if (role < 2) {
            bf16* Ot = (role == 0) ? Qt : Kt;
            union { ushort4 u4; bf16 h[4]; } pk;
            #pragma unroll
            for (int r = 0; r < 4; ++r) pk.h[r] = (bf16)acc[r];
            *(ushort4*)(Ot + ((size_t)b * N_ + n) * C_ + dt * 16 + quad * 4) = pk.u4;
        } else {
            #pragma unroll
            for (int r = 0; r < 4; ++r)
                Vt[((size_t)b * C_ + dt * 16 + quad * 4 + r) * (size_t)M_ + n] = (bf16)acc[r];
        }
    }
}

// ===========================================================================
// Kernel 2 (v5): chunk-skewed pipeline. S is carried in registers one body;
// each body executes QK(j+1) [MFMA] || SM(j) [VALU] || PV(j) [MFMA], so the
// softmax VALU burst hides under the QK MFMA window inside the same wave
// (r4/r5 lockstep serialized the LDS/VALU/MFMA pipes: their SUM was the
// wall). Two S register sets alternate via a 2-body unrolled loop (static
// indexing). K/V double-buffered (128 KB), one vmcnt(0)+barrier per body,
// staging via running pointers (+= const stride, no per-body addr math).
// Math per element identical to the round-3/4 verified kernel.
// ===========================================================================
__global__ __launch_bounds__(512) void attn_kernel(
    const bf16* __restrict__ Qt, const bf16* __restrict__ Kt,
    const bf16* __restrict__ Vt, const float* __restrict__ x1,
    float* __restrict__ out) {
    __shared__ __align__(16) char smem[132096];
    // kb0 @ 0, kb1 @ 32768   [128 key][16 slots, slot^=key&15]
    // vb0 @ 65536, vb1 @ 98304 [128 c ][16 slots, slot^=c&15]

    const int t = threadIdx.x;
    const int w = t >> 6;
    const int lane = t & 63;
    const int col = lane & 31;
    const int hi = lane >> 5;
    const int kg = w & 3;            // key-group (32 keys of 128-key chunk)
    const int qg = w >> 2;           // query-group (32 of the 64 queries)

    // XCD-aware decode: batch -> XCD pair (K+V of one batch L2-resident)
    const int g0 = blockIdx.x;
    const int xcd = g0 & 7;
    const int b = xcd >> 1;
    const int qt = (xcd & 1) + ((g0 >> 3) << 1);   // 64 q-tiles of 64
    const int n0 = qt * 64;

    const float KS = 0.12752107168406815f;  // log2(e)/sqrt(128)

    const bf16* Kbase = Kt + (size_t)b * M_ * C_;
    const bf16* Vbase = Vt + (size_t)b * C_ * M_;

    // Q fragments (B-operand of swapped QK): lane col = query, k = hi*8+j
    bf16x8 qf[8];
    {
        const bf16* Qb = Qt + ((size_t)b * N_ + n0 + qg * 32 + col) * C_ + hi * 8;
        #pragma unroll
        for (int cs = 0; cs < 8; ++cs)
            qf[cs] = *(const bf16x8*)(Qb + cs * 16);
    }

    f32x16 oacc[4];
    #pragma unroll
    for (int i = 0; i < 4; ++i)
        #pragma unroll
        for (int j = 0; j < 16; ++j) oacc[i][j] = 0.f;
    float lacc = 0.f;

    const int key_l = (kg << 5) + col;
    const int kxor = (key_l & 15) << 4;

    // running staging pointers (pre-swizzled source addressing)
    const bf16* kpp[4];
    const bf16* vpp[4];
    #pragma unroll
    for (int i = 0; i < 4; ++i) {
        int g = ((w << 2) + i) * 64 + lane;
        int row = g >> 4;                    // key (K) / channel (V)
        int sp = (g & 15) ^ (row & 15);      // inverse-swizzled SOURCE slot
        kpp[i] = Kbase + (size_t)row * C_ + sp * 8;
        vpp[i] = Vbase + (size_t)row * M_ + sp * 8;
    }

    auto stageK = [&](char* dst) {
        #pragma unroll
        for (int i = 0; i < 4; ++i) {
            gll16(kpp[i], (bf16*)dst + ((w << 2) + i) * 512);
            kpp[i] += 128 * C_;              // next 128-key chunk
        }
    };
    auto stageV = [&](char* dst) {
        #pragma unroll
        for (int i = 0; i < 4; ++i) {
            gll16(vpp[i], (bf16*)dst + ((w << 2) + i) * 512);
            vpp[i] += 128;                   // next 128-key chunk (col shift)
        }
    };

    // prologue FIFO: K0 -> kb0, V0 -> vb0, K1 -> kb1   (12 loads)
    stageK(smem);
    stageV(smem + 65536);
    stageK(smem + 32768);

    f32x16 sA0, sA1, sB0, sB1;

    // QK MFMA cluster: chunk read from kbBuf -> (T0,T1)
    auto qkc = [&](const char* kbBuf, f32x16& T0, f32x16& T1) {
        #pragma unroll
        for (int q = 0; q < 16; ++q) { T0[q] = 0.f; T1[q] = 0.f; }
        const char* kbp = kbBuf + key_l * 256;
        __builtin_amdgcn_s_setprio(1);
        #pragma unroll
        for (int cs = 0; cs < 4; ++cs) {
            bf16x8 kf = *(const bf16x8*)(kbp + ((((cs << 1) + hi) << 4) ^ kxor));
            T0 = MFMA32(kf, qf[cs], T0);
        }
        #pragma unroll
        for (int cs = 4; cs < 8; ++cs) {
            bf16x8 kf = *(const bf16x8*)(kbp + ((((cs << 1) + hi) << 4) ^ kxor));
            T1 = MFMA32(kf, qf[cs], T1);
        }
        __builtin_amdgcn_s_setprio(0);
    };

    // SM(j) from (S0,S1) -> af0/af1 ; PV(j) from vbBuf
    auto smpv = [&](f32x16& S0, f32x16& S1, const char* vbBuf) {
        float p[16];
        #pragma unroll
        for (int r = 0; r < 16; ++r) {
            float e = fminf((S0[r] + S1[r]) * KS, 60.f);
            p[r] = __builtin_amdgcn_exp2f(e);
        }
        {
            float s01 = (p[0] + p[1]) + (p[2] + p[3]);
            float s23 = (p[4] + p[5]) + (p[6] + p[7]);
            float s45 = (p[8] + p[9]) + (p[10] + p[11]);
            float s67 = (p[12] + p[13]) + (p[14] + p[15]);
            lacc += (s01 + s23) + (s45 + s67);
        }
        unsigned W0 = cvtpk(p[0], p[1]),  W1 = cvtpk(p[2], p[3]);
        unsigned W2 = cvtpk(p[4], p[5]),  W3 = cvtpk(p[6], p[7]);
        unsigned W4 = cvtpk(p[8], p[9]),  W5 = cvtpk(p[10], p[11]);
        unsigned W6 = cvtpk(p[12], p[13]), W7 = cvtpk(p[14], p[15]);
        unsigned X0 = hi ? W0 : W2, X1 = hi ? W1 : W3;
        unsigned Y0 = hi ? W4 : W6, Y1 = hi ? W5 : W7;
        X0 = __shfl_xor(X0, 32, 64);  X1 = __shfl_xor(X1, 32, 64);
        Y0 = __shfl_xor(Y0, 32, 64);  Y1 = __shfl_xor(Y1, 32, 64);
        uint4 u0, u1;
        u0.x = hi ? X0 : W0;  u0.y = hi ? X1 : W1;
        u0.z = hi ? W2 : X0;  u0.w = hi ? W3 : X1;
        u1.x = hi ? Y0 : W4;  u1.y = hi ? Y1 : W5;
        u1.z = hi ? W6 : Y0;  u1.w = hi ? W7 : Y1;
        bf16x8 af0 = __builtin_bit_cast(bf16x8, u0);   // keys hi*8   .. +7
        bf16x8 af1 = __builtin_bit_cast(bf16x8, u1);   // keys 16+hi*8.. +7

        __builtin_amdgcn_s_setprio(1);
        #pragma unroll
        for (int ct = 0; ct < 4; ++ct) {
            int c = (ct << 5) + col;
            const char* vbp = vbBuf + c * 256;
            int vxor = (c & 15) << 4;
            bf16x8 vf0 = *(const bf16x8*)(vbp + ((((kg << 2) + hi) << 4) ^ vxor));
            bf16x8 vf1 = *(const bf16x8*)(vbp + ((((kg << 2) + 2 + hi) << 4) ^ vxor));
            oacc[ct] = MFMA32(af0, vf0, oacc[ct]);
            oacc[ct] = MFMA32(af1, vf1, oacc[ct]);
        }
        __builtin_amdgcn_s_setprio(0);
    };

    // peel: K0 landed for everyone -> compute S(0)
    asm volatile("s_waitcnt vmcnt(8)" ::: "memory");
    __builtin_amdgcn_sched_barrier(0);
    __builtin_amdgcn_s_barrier();
    __builtin_amdgcn_sched_barrier(0);
    qkc(smem, sA0, sA1);

    for (int jp = 0; jp < 16; ++jp) {
        const int j0 = jp * 2, j1 = j0 + 1;

        // ---- body A (even j0): SM/PV on j0 with S=A, QK(j0+1)->B ----
        asm volatile("s_waitcnt vmcnt(0)" ::: "memory");   // V(j0), K(j0+1) landed
        __builtin_amdgcn_sched_barrier(0);
        __builtin_amdgcn_s_barrier();                      // published; prev reads retired
        __builtin_amdgcn_sched_barrier(0);
        if (j0 < 31) stageV(smem + 98304);                 // V(j0+1) -> vb1
        if (j0 < 30) stageK(smem);                         // K(j0+2) -> kb0
        if (j0 < 31) qkc(smem + 32768, sB0, sB1);          // QK(j0+1) from kb1
        smpv(sA0, sA1, smem + 65536);                      // SM(j0)+PV(j0), vb0
        asm volatile("s_waitcnt lgkmcnt(0)" ::: "memory");
        __builtin_amdgcn_sched_barrier(0);

        // ---- body B (odd j1): SM/PV on j1 with S=B, QK(j1+1)->A ----
        asm volatile("s_waitcnt vmcnt(0)" ::: "memory");   // V(j1), K(j1+1) landed
        __builtin_amdgcn_sched_barrier(0);
        __builtin_amdgcn_s_barrier();
        __builtin_amdgcn_sched_barrier(0);
        if (j1 < 31) stageV(smem + 65536);                 // V(j1+1) -> vb0
        if (j1 < 30) stageK(smem + 32768);                 // K(j1+2) -> kb1
        if (j1 < 31) qkc(smem, sA0, sA1);                  // QK(j1+1) from kb0
        smpv(sB0, sB1, smem + 98304);                      // SM(j1)+PV(j1), vb1
        asm volatile("s_waitcnt lgkmcnt(0)" ::: "memory");
        __builtin_amdgcn_sched_barrier(0);
    }

    __builtin_amdgcn_s_barrier();   // all LDS reads retired; reuse smem

    // ---- cross-wave merge of key-group partials ----
    float* obuf = (float*)smem;                 // [4 kg][64 q][128 c]  128 KB
    float* lps  = (float*)(smem + 131072);      // [4 kg][64 q]

    lacc += __shfl_xor(lacc, 32, 64);           // + other hi-half's 16 keys
    if (hi == 0) lps[(kg << 6) + (qg << 5) + col] = lacc;

    #pragma unroll
    for (int ct = 0; ct < 4; ++ct)
        #pragma unroll
        for (int r = 0; r < 16; ++r) {
            int q = (r & 3) + ((r >> 2) << 3) + (hi << 2);
            obuf[kg * 8192 + ((qg << 5) + q) * 128 + (ct << 5) + col] = oacc[ct][r];
        }
    __syncthreads();

    const int c2 = lane << 1;                   // 2 channels per lane
    #pragma unroll
    for (int j = 0; j < 8; ++j) {
        int q = (w << 3) + j;                   // wave w finalizes queries w*8..+7
        float s0 = 0.f, s1 = 0.f;
        #pragma unroll
        for (int pp = 0; pp < 4; ++pp) {
            float2 v = *(const float2*)&obuf[pp * 8192 + q * 128 + c2];
            s0 += v.x; s1 += v.y;
        }
        float lsum = lps[q] + lps[64 + q] + lps[128 + q] + lps[192 + q];
        float linv = 1.0f / lsum;
        int n = n0 + q;
        float o0 = s0 * linv + x1[((size_t)b * C_ + c2) * N_ + n];
        float o1 = s1 * linv + x1[((size_t)b * C_ + c2 + 1) * N_ + n];
        *(float2*)&out[((size_t)b * N_ + n) * C_ + c2] = make_float2(o0, o1);
    }
}

// ---------------------------------------------------------------------------
extern "C" void kernel_launch(void* const* d_in, const int* in_sizes, int n_in,
                              void* d_out, int out_size, void* d_ws, size_t ws_size,
                              hipStream_t stream) {
    const float* x1   = (const float*)d_in[0];
    const float* p1   = (const float*)d_in[1];
    const float* x2   = (const float*)d_in[2];
    const float* p2   = (const float*)d_in[3];
    const float* Wq   = (const float*)d_in[4];
    const float* Wk   = (const float*)d_in[5];
    const float* Wv   = (const float*)d_in[6];
    const float* Wpos = (const float*)d_in[7];
    float* out = (float*)d_out;

    bf16* Qt = (bf16*)d_ws;                 // [B][N][C]
    bf16* Kt = Qt + (size_t)B_ * N_ * C_;   // [B][M][C]
    bf16* Vt = Kt + (size_t)B_ * M_ * C_;   // [B][C][M]

    // bf16 W parked in the head of out (96 KB of 8 MB); proj reads it, then
    // attn fully overwrites out.
    bf16* Wb = (bf16*)d_out;

    wcvt_kernel<<<dim3(48), dim3(256), 0, stream>>>(Wq, Wk, Wv, Wb);
    proj_kernel<<<dim3(64, B_), dim3(768), 0, stream>>>(
        x1, p1, x2, p2, Wb, Wpos, Qt, Kt, Vt);
    attn_kernel<<<dim3(256), dim3(512), 0, stream>>>(Qt, Kt, Vt, x1, out);
}

// Round 7
// 143.809 us; speedup vs baseline: 1.8274x; 1.0005x over previous
//
#include <hip/hip_runtime.h>
#include <hip/hip_bf16.h>

#define B_ 4
#define C_ 128
#define N_ 4096
#define M_ 4096

typedef __bf16 bf16;
typedef __bf16 bf16x8 __attribute__((ext_vector_type(8)));
typedef float f32x4 __attribute__((ext_vector_type(4)));
typedef float f32x16 __attribute__((ext_vector_type(16)));

#define MFMA16(a, b, c) __builtin_amdgcn_mfma_f32_16x16x32_bf16(a, b, c, 0, 0, 0)
#define MFMA32(a, b, c) __builtin_amdgcn_mfma_f32_32x32x16_bf16(a, b, c, 0, 0, 0)

// async 16B global -> LDS (dest = wave-uniform base + lane*16)
__device__ inline void gll16(const bf16* g, bf16* l) {
    __builtin_amdgcn_global_load_lds(
        (const __attribute__((address_space(1))) void*)g,
        (__attribute__((address_space(3))) void*)l, 16, 0, 0);
}

// v_cvt_pk_bf16_f32: pack two f32 -> u32 of 2 bf16 (lo = a, hi = b)
__device__ inline unsigned cvtpk(float a, float b) {
    unsigned r;
    asm("v_cvt_pk_bf16_f32 %0, %1, %2" : "=v"(r) : "v"(a), "v"(b));
    return r;
}

// ===========================================================================
// Kernel 0: one-shot W f32->bf16 conversion (parked in head of d_out, which
// attn fully overwrites later).
// ===========================================================================
__global__ __launch_bounds__(256) void wcvt_kernel(
    const float* __restrict__ Wq, const float* __restrict__ Wk,
    const float* __restrict__ Wv, bf16* __restrict__ Wb) {
    int i = (blockIdx.x * 256 + threadIdx.x) * 4;        // 49152 elements total
    const float* src = (i < 16384) ? Wq : (i < 32768) ? Wk : Wv;
    int off = i & 16383;
    float4 v = *(const float4*)(src + off);
    union { ushort4 u4; bf16 h[4]; } pk;
    pk.h[0] = (bf16)v.x; pk.h[1] = (bf16)v.y;
    pk.h[2] = (bf16)v.z; pk.h[3] = (bf16)v.w;
    *(ushort4*)(Wb + i) = pk.u4;
}

// ===========================================================================
// Kernel 1 (REWRITTEN): role-split projections. Grid (64 ntiles, 4 b, 3 role)
// = 768 blocks x 256 thr (4 waves), 17.4 KB LDS -> 3 blocks/CU co-resident
// (old: one 12-wave block/CU, 3 serial phases, nothing to overlap with).
// role 0: Q = Wq(x1+Wpos p1) -> Qt[b][n][c]   (SWAPPED mfma: D=[n][c],
// role 1: K = Wk(x2+Wpos p2) -> Kt[b][m][c]    stores are 4x32B segments
// role 2: V = Wv(x2)         -> Vt[b][c][m]    instead of 64x8B scatter)
// ===========================================================================
__global__ __launch_bounds__(256) void proj_kernel(
    const float* __restrict__ x1, const float* __restrict__ p1,
    const float* __restrict__ x2, const float* __restrict__ p2,
    const bf16* __restrict__ Wb, const float* __restrict__ Wpos,
    bf16* __restrict__ Qt, bf16* __restrict__ Kt, bf16* __restrict__ Vt) {
    __shared__ __align__(16) bf16 xt[64 * 136];        // [n][c] stride 136
    __shared__ float pp[3 * 64], wls[384];

    const int t = threadIdx.x;
    const int b = blockIdx.y;
    const int role = blockIdx.z;
    const int n0 = blockIdx.x * 64;

    const float* xs = (role == 0) ? x1 : x2;
    const float* ps = (role == 0) ? p1 : p2;

    // ---- phase A: stage pos-inputs (roles 0/1 only) ----
    if (role < 2) {
        if (t < 48) {
            int k3 = t / 16, i4 = (t & 15) * 4;
            *(float4*)&pp[k3 * 64 + i4] =
                *(const float4*)(ps + ((size_t)b * 3 + k3) * N_ + n0 + i4);
        } else if (t < 144) {
            int i4 = (t - 48) * 4;
            *(float4*)&wls[i4] = *(const float4*)(Wpos + i4);
        }
    }
    __syncthreads();

    // ---- phase B: stage x tile (+pos fold), transpose to [n][c] bf16 ----
    #pragma unroll
    for (int k = 0; k < 8; ++k) {
        int s = t + k * 256;
        int c = s >> 4, n4 = (s & 15) * 4;
        float4 xv = *(const float4*)(xs + ((size_t)b * C_ + c) * N_ + n0 + n4);
        const float* xa = &xv.x;
        if (role < 2) {
            float w0 = wls[c * 3 + 0], w1 = wls[c * 3 + 1], w2 = wls[c * 3 + 2];
            #pragma unroll
            for (int j = 0; j < 4; ++j) {
                float pos = w0 * pp[n4 + j] + w1 * pp[64 + n4 + j] + w2 * pp[128 + n4 + j];
                xt[(n4 + j) * 136 + c] = (bf16)(xa[j] + pos);
            }
        } else {
            #pragma unroll
            for (int j = 0; j < 4; ++j)
                xt[(n4 + j) * 136 + c] = (bf16)xa[j];
        }
    }
    __syncthreads();

    // ---- phase C: MFMA, 4 waves x 16 n-points each ----
    const int w = t >> 6;
    const int lane = t & 63;
    const int col = lane & 15, quad = lane >> 4;
    const int nl = w * 16 + col;

    const bf16* Wm = Wb + role * 16384;   // bf16 W, [d][c] row-major

    bf16x8 bx[4];
    #pragma unroll
    for (int cs = 0; cs < 4; ++cs)
        bx[cs] = *(const bf16x8*)&xt[nl * 136 + cs * 32 + quad * 8];

    if (role < 2) {
        bf16* Ot = (role == 0) ? Qt : Kt;
        #pragma unroll
        for (int dt = 0; dt < 8; ++dt) {
            f32x4 acc = {0.f, 0.f, 0.f, 0.f};
            #pragma unroll
            for (int cs = 0; cs < 4; ++cs) {
                bf16x8 wf = *(const bf16x8*)(Wm + (dt * 16 + col) * 128 + cs * 32 + quad * 8);
                acc = MFMA16(bx[cs], wf, acc);        // SWAPPED: D[n-rows][c-cols]
            }
            #pragma unroll
            for (int r = 0; r < 4; ++r) {
                int n = n0 + w * 16 + quad * 4 + r;   // row = quad*4+r
                Ot[((size_t)b * N_ + n) * C_ + dt * 16 + col] = (bf16)acc[r];
            }
        }
    } else {
        #pragma unroll
        for (int dt = 0; dt < 8; ++dt) {
            f32x4 acc = {0.f, 0.f, 0.f, 0.f};
            #pragma unroll
            for (int cs = 0; cs < 4; ++cs) {
                bf16x8 wf = *(const bf16x8*)(Wm + (dt * 16 + col) * 128 + cs * 32 + quad * 8);
                acc = MFMA16(wf, bx[cs], acc);        // D[c-rows][n-cols]
            }
            #pragma unroll
            for (int r = 0; r < 4; ++r)
                Vt[((size_t)b * C_ + dt * 16 + quad * 4 + r) * (size_t)M_ + n0 + nl] = (bf16)acc[r];
        }
    }
}

// ===========================================================================
// Kernel 2 (UNCHANGED from round 6 — 58.2 us verified): chunk-skewed
// pipeline, S carried in registers one body; QK(j+1) || SM(j) || PV(j).
// ===========================================================================
__global__ __launch_bounds__(512) void attn_kernel(
    const bf16* __restrict__ Qt, const bf16* __restrict__ Kt,
    const bf16* __restrict__ Vt, const float* __restrict__ x1,
    float* __restrict__ out) {
    __shared__ __align__(16) char smem[132096];
    // kb0 @ 0, kb1 @ 32768   [128 key][16 slots, slot^=key&15]
    // vb0 @ 65536, vb1 @ 98304 [128 c ][16 slots, slot^=c&15]

    const int t = threadIdx.x;
    const int w = t >> 6;
    const int lane = t & 63;
    const int col = lane & 31;
    const int hi = lane >> 5;
    const int kg = w & 3;            // key-group (32 keys of 128-key chunk)
    const int qg = w >> 2;           // query-group (32 of the 64 queries)

    // XCD-aware decode: batch -> XCD pair (K+V of one batch L2-resident)
    const int g0 = blockIdx.x;
    const int xcd = g0 & 7;
    const int b = xcd >> 1;
    const int qt = (xcd & 1) + ((g0 >> 3) << 1);   // 64 q-tiles of 64
    const int n0 = qt * 64;

    const float KS = 0.12752107168406815f;  // log2(e)/sqrt(128)

    const bf16* Kbase = Kt + (size_t)b * M_ * C_;
    const bf16* Vbase = Vt + (size_t)b * C_ * M_;

    // Q fragments (B-operand of swapped QK): lane col = query, k = hi*8+j
    bf16x8 qf[8];
    {
        const bf16* Qb = Qt + ((size_t)b * N_ + n0 + qg * 32 + col) * C_ + hi * 8;
        #pragma unroll
        for (int cs = 0; cs < 8; ++cs)
            qf[cs] = *(const bf16x8*)(Qb + cs * 16);
    }

    f32x16 oacc[4];
    #pragma unroll
    for (int i = 0; i < 4; ++i)
        #pragma unroll
        for (int j = 0; j < 16; ++j) oacc[i][j] = 0.f;
    float lacc = 0.f;

    const int key_l = (kg << 5) + col;
    const int kxor = (key_l & 15) << 4;

    // running staging pointers (pre-swizzled source addressing)
    const bf16* kpp[4];
    const bf16* vpp[4];
    #pragma unroll
    for (int i = 0; i < 4; ++i) {
        int g = ((w << 2) + i) * 64 + lane;
        int row = g >> 4;                    // key (K) / channel (V)
        int sp = (g & 15) ^ (row & 15);      // inverse-swizzled SOURCE slot
        kpp[i] = Kbase + (size_t)row * C_ + sp * 8;
        vpp[i] = Vbase + (size_t)row * M_ + sp * 8;
    }

    auto stageK = [&](char* dst) {
        #pragma unroll
        for (int i = 0; i < 4; ++i) {
            gll16(kpp[i], (bf16*)dst + ((w << 2) + i) * 512);
            kpp[i] += 128 * C_;              // next 128-key chunk
        }
    };
    auto stageV = [&](char* dst) {
        #pragma unroll
        for (int i = 0; i < 4; ++i) {
            gll16(vpp[i], (bf16*)dst + ((w << 2) + i) * 512);
            vpp[i] += 128;                   // next 128-key chunk (col shift)
        }
    };

    // prologue FIFO: K0 -> kb0, V0 -> vb0, K1 -> kb1   (12 loads)
    stageK(smem);
    stageV(smem + 65536);
    stageK(smem + 32768);

    f32x16 sA0, sA1, sB0, sB1;

    // QK MFMA cluster: chunk read from kbBuf -> (T0,T1)
    auto qkc = [&](const char* kbBuf, f32x16& T0, f32x16& T1) {
        #pragma unroll
        for (int q = 0; q < 16; ++q) { T0[q] = 0.f; T1[q] = 0.f; }
        const char* kbp = kbBuf + key_l * 256;
        __builtin_amdgcn_s_setprio(1);
        #pragma unroll
        for (int cs = 0; cs < 4; ++cs) {
            bf16x8 kf = *(const bf16x8*)(kbp + ((((cs << 1) + hi) << 4) ^ kxor));
            T0 = MFMA32(kf, qf[cs], T0);
        }
        #pragma unroll
        for (int cs = 4; cs < 8; ++cs) {
            bf16x8 kf = *(const bf16x8*)(kbp + ((((cs << 1) + hi) << 4) ^ kxor));
            T1 = MFMA32(kf, qf[cs], T1);
        }
        __builtin_amdgcn_s_setprio(0);
    };

    // SM(j) from (S0,S1) -> af0/af1 ; PV(j) from vbBuf
    auto smpv = [&](f32x16& S0, f32x16& S1, const char* vbBuf) {
        float p[16];
        #pragma unroll
        for (int r = 0; r < 16; ++r) {
            float e = fminf((S0[r] + S1[r]) * KS, 60.f);
            p[r] = __builtin_amdgcn_exp2f(e);
        }
        {
            float s01 = (p[0] + p[1]) + (p[2] + p[3]);
            float s23 = (p[4] + p[5]) + (p[6] + p[7]);
            float s45 = (p[8] + p[9]) + (p[10] + p[11]);
            float s67 = (p[12] + p[13]) + (p[14] + p[15]);
            lacc += (s01 + s23) + (s45 + s67);
        }
        unsigned W0 = cvtpk(p[0], p[1]),  W1 = cvtpk(p[2], p[3]);
        unsigned W2 = cvtpk(p[4], p[5]),  W3 = cvtpk(p[6], p[7]);
        unsigned W4 = cvtpk(p[8], p[9]),  W5 = cvtpk(p[10], p[11]);
        unsigned W6 = cvtpk(p[12], p[13]), W7 = cvtpk(p[14], p[15]);
        unsigned X0 = hi ? W0 : W2, X1 = hi ? W1 : W3;
        unsigned Y0 = hi ? W4 : W6, Y1 = hi ? W5 : W7;
        X0 = __shfl_xor(X0, 32, 64);  X1 = __shfl_xor(X1, 32, 64);
        Y0 = __shfl_xor(Y0, 32, 64);  Y1 = __shfl_xor(Y1, 32, 64);
        uint4 u0, u1;
        u0.x = hi ? X0 : W0;  u0.y = hi ? X1 : W1;
        u0.z = hi ? W2 : X0;  u0.w = hi ? W3 : X1;
        u1.x = hi ? Y0 : W4;  u1.y = hi ? Y1 : W5;
        u1.z = hi ? W6 : Y0;  u1.w = hi ? W7 : Y1;
        bf16x8 af0 = __builtin_bit_cast(bf16x8, u0);   // keys hi*8   .. +7
        bf16x8 af1 = __builtin_bit_cast(bf16x8, u1);   // keys 16+hi*8.. +7

        __builtin_amdgcn_s_setprio(1);
        #pragma unroll
        for (int ct = 0; ct < 4; ++ct) {
            int c = (ct << 5) + col;
            const char* vbp = vbBuf + c * 256;
            int vxor = (c & 15) << 4;
            bf16x8 vf0 = *(const bf16x8*)(vbp + ((((kg << 2) + hi) << 4) ^ vxor));
            bf16x8 vf1 = *(const bf16x8*)(vbp + ((((kg << 2) + 2 + hi) << 4) ^ vxor));
            oacc[ct] = MFMA32(af0, vf0, oacc[ct]);
            oacc[ct] = MFMA32(af1, vf1, oacc[ct]);
        }
        __builtin_amdgcn_s_setprio(0);
    };

    // peel: K0 landed for everyone -> compute S(0)
    asm volatile("s_waitcnt vmcnt(8)" ::: "memory");
    __builtin_amdgcn_sched_barrier(0);
    __builtin_amdgcn_s_barrier();
    __builtin_amdgcn_sched_barrier(0);
    qkc(smem, sA0, sA1);

    for (int jp = 0; jp < 16; ++jp) {
        const int j0 = jp * 2, j1 = j0 + 1;

        // ---- body A (even j0): SM/PV on j0 with S=A, QK(j0+1)->B ----
        asm volatile("s_waitcnt vmcnt(0)" ::: "memory");   // V(j0), K(j0+1) landed
        __builtin_amdgcn_sched_barrier(0);
        __builtin_amdgcn_s_barrier();                      // published; prev reads retired
        __builtin_amdgcn_sched_barrier(0);
        if (j0 < 31) stageV(smem + 98304);                 // V(j0+1) -> vb1
        if (j0 < 30) stageK(smem);                         // K(j0+2) -> kb0
        if (j0 < 31) qkc(smem + 32768, sB0, sB1);          // QK(j0+1) from kb1
        smpv(sA0, sA1, smem + 65536);                      // SM(j0)+PV(j0), vb0
        asm volatile("s_waitcnt lgkmcnt(0)" ::: "memory");
        __builtin_amdgcn_sched_barrier(0);

        // ---- body B (odd j1): SM/PV on j1 with S=B, QK(j1+1)->A ----
        asm volatile("s_waitcnt vmcnt(0)" ::: "memory");   // V(j1), K(j1+1) landed
        __builtin_amdgcn_sched_barrier(0);
        __builtin_amdgcn_s_barrier();
        __builtin_amdgcn_sched_barrier(0);
        if (j1 < 31) stageV(smem + 65536);                 // V(j1+1) -> vb0
        if (j1 < 30) stageK(smem + 32768);                 // K(j1+2) -> kb1
        if (j1 < 31) qkc(smem, sA0, sA1);                  // QK(j1+1) from kb0
        smpv(sB0, sB1, smem + 98304);                      // SM(j1)+PV(j1), vb1
        asm volatile("s_waitcnt lgkmcnt(0)" ::: "memory");
        __builtin_amdgcn_sched_barrier(0);
    }

    __builtin_amdgcn_s_barrier();   // all LDS reads retired; reuse smem

    // ---- cross-wave merge of key-group partials ----
    float* obuf = (float*)smem;                 // [4 kg][64 q][128 c]  128 KB
    float* lps  = (float*)(smem + 131072);      // [4 kg][64 q]

    lacc += __shfl_xor(lacc, 32, 64);           // + other hi-half's 16 keys
    if (hi == 0) lps[(kg << 6) + (qg << 5) + col] = lacc;

    #pragma unroll
    for (int ct = 0; ct < 4; ++ct)
        #pragma unroll
        for (int r = 0; r < 16; ++r) {
            int q = (r & 3) + ((r >> 2) << 3) + (hi << 2);
            obuf[kg * 8192 + ((qg << 5) + q) * 128 + (ct << 5) + col] = oacc[ct][r];
        }
    __syncthreads();

    const int c2 = lane << 1;                   // 2 channels per lane
    #pragma unroll
    for (int j = 0; j < 8; ++j) {
        int q = (w << 3) + j;                   // wave w finalizes queries w*8..+7
        float s0 = 0.f, s1 = 0.f;
        #pragma unroll
        for (int pp = 0; pp < 4; ++pp) {
            float2 v = *(const float2*)&obuf[pp * 8192 + q * 128 + c2];
            s0 += v.x; s1 += v.y;
        }
        float lsum = lps[q] + lps[64 + q] + lps[128 + q] + lps[192 + q];
        float linv = 1.0f / lsum;
        int n = n0 + q;
        float o0 = s0 * linv + x1[((size_t)b * C_ + c2) * N_ + n];
        float o1 = s1 * linv + x1[((size_t)b * C_ + c2 + 1) * N_ + n];
        *(float2*)&out[((size_t)b * N_ + n) * C_ + c2] = make_float2(o0, o1);
    }
}

// ---------------------------------------------------------------------------
extern "C" void kernel_launch(void* const* d_in, const int* in_sizes, int n_in,
                              void* d_out, int out_size, void* d_ws, size_t ws_size,
                              hipStream_t stream) {
    const float* x1   = (const float*)d_in[0];
    const float* p1   = (const float*)d_in[1];
    const float* x2   = (const float*)d_in[2];
    const float* p2   = (const float*)d_in[3];
    const float* Wq   = (const float*)d_in[4];
    const float* Wk   = (const float*)d_in[5];
    const float* Wv   = (const float*)d_in[6];
    const float* Wpos = (const float*)d_in[7];
    float* out = (float*)d_out;

    bf16* Qt = (bf16*)d_ws;                 // [B][N][C]
    bf16* Kt = Qt + (size_t)B_ * N_ * C_;   // [B][M][C]
    bf16* Vt = Kt + (size_t)B_ * M_ * C_;   // [B][C][M]

    // bf16 W parked in the head of out (96 KB of 8 MB); proj reads it, then
    // attn fully overwrites out.
    bf16* Wb = (bf16*)d_out;

    wcvt_kernel<<<dim3(48), dim3(256), 0, stream>>>(Wq, Wk, Wv, Wb);
    proj_kernel<<<dim3(64, B_, 3), dim3(256), 0, stream>>>(
        x1, p1, x2, p2, Wb, Wpos, Qt, Kt, Vt);
    attn_kernel<<<dim3(256), dim3(512), 0, stream>>>(Qt, Kt, Vt, x1, out);
}